// Round 11
// baseline (132.234 us; speedup 1.0000x reference)
//
#include <hip/hip_runtime.h>
#include <hip/hip_bf16.h>
#include <hip/hip_fp16.h>

// ---------------------------------------------------------------------------
// Multihead attention with flat-reshape head split + mean-threshold mask.
//   B=8 S=1024 D=512 H=8 -> 64 independent attention problems of (1024 x 64);
//   problem (h,b) = 128 consecutive rows of the 8192x512 projected matrix
//   reinterpreted as 1024x64.
// Precision: Q/K path 3-term bf16 split -> fp32-accurate scores. V/P/O fp16.
// Round-11 (k_attn only; numerics bit-identical):
//   * Round-10 lesson: LDS BW was NOT the limiter (2x q-reuse = null).
//     Limiter = dependency-chain stall at 2 waves/SIMD; wave count was
//     grid-capped (512 blocks / 256 CU).
//   * New shape: grid (64 p, 16 qt) = 1024 blocks x 4 waves x 16 q;
//     chunk = 32 keys double-buffered -> LDS 24 KB -> 4 blocks/CU ->
//     ALL 1024 blocks co-resident, 16 waves/CU = 4/SIMD (2x round 10).
//   * Swizzles re-derived for 32-key geometry (both 2-way = free).
// ---------------------------------------------------------------------------

typedef _Float16 f16;
typedef __attribute__((ext_vector_type(4))) _Float16 f16x4;
typedef __attribute__((ext_vector_type(8))) _Float16 f16x8;
typedef __attribute__((ext_vector_type(8))) short bf16x8;
typedef __attribute__((ext_vector_type(4))) float f32x4;

#define MFMA16(a, b, c) __builtin_amdgcn_mfma_f32_16x16x32_f16((a), (b), (c), 0, 0, 0)
#define MFMAB16(a, b, c) __builtin_amdgcn_mfma_f32_16x16x32_bf16((a), (b), (c), 0, 0, 0)
#define MFMAPV(a, b, c) __builtin_amdgcn_mfma_f32_16x16x16f16((a), (b), (c), 0, 0, 0)

#if defined(__has_builtin) && __has_builtin(__builtin_amdgcn_exp2f)
#define EXPFN(x) __builtin_amdgcn_exp2f(x)
#define QPROJ_SCALE (0.04419417382415922f * 1.4426950408889634f)
#else
#define EXPFN(x) __expf(x)
#define QPROJ_SCALE 0.04419417382415922f
#endif

// async global->LDS, 16B per lane; LDS dst = wave-uniform base + lane*16
#define GLL16(gp, lp)                                       \
  __builtin_amdgcn_global_load_lds(                         \
      (const __attribute__((address_space(1))) void*)(gp),  \
      (__attribute__((address_space(3))) void*)(lp), 16, 0, 0)

__device__ __forceinline__ float b2f(short s) {
  return __uint_as_float(((unsigned)(unsigned short)s) << 16);
}

__device__ __forceinline__ void splitbf(float v, short& h, short& l) {
  unsigned short hu = __bfloat16_as_ushort(__float2bfloat16(v));
  h = (short)hu;
  float hf = __uint_as_float(((unsigned)hu) << 16);
  l = (short)__bfloat16_as_ushort(__float2bfloat16(v - hf));
}

// --------------------------- weight transpose+convert ----------------------
__global__ void k_wt(const float* __restrict__ w0, const float* __restrict__ w1,
                     const float* __restrict__ w2, const float* __restrict__ w3,
                     short* __restrict__ qh, short* __restrict__ ql,
                     short* __restrict__ kh, short* __restrict__ kl,
                     f16* __restrict__ vt, f16* __restrict__ ot) {
  const float* W;
  switch (blockIdx.z) {
    case 0: W = w0; break;
    case 1: W = w1; break;
    case 2: W = w2; break;
    default: W = w3; break;
  }
  __shared__ float t[32][33];
  int bx = blockIdx.x, by = blockIdx.y;
  int tx = threadIdx.x, ty = threadIdx.y;  // 32 x 8
#pragma unroll
  for (int i = 0; i < 32; i += 8)
    t[ty + i][tx] = W[(size_t)(by * 32 + ty + i) * 512 + bx * 32 + tx];
  __syncthreads();
#pragma unroll
  for (int i = 0; i < 32; i += 8) {
    size_t idx = (size_t)(bx * 32 + ty + i) * 512 + by * 32 + tx;
    float v = t[tx][ty + i];
    if (blockIdx.z < 2) {
      short h, l;
      splitbf(v, h, l);
      if (blockIdx.z == 0) { qh[idx] = h; ql[idx] = l; }
      else { kh[idx] = h; kl[idx] = l; }
    } else {
      if (blockIdx.z == 2) vt[idx] = (f16)v;
      else ot[idx] = (f16)v;
    }
  }
}

// ------------------ input split (x,y -> bf16 hi/lo; y -> f16) --------------
__global__ __launch_bounds__(256) void k_split(
    const float* __restrict__ x, const float* __restrict__ y,
    short* __restrict__ Xh, short* __restrict__ Xl, short* __restrict__ Yh,
    short* __restrict__ Yl, f16* __restrict__ Ym) {
  const float* src = blockIdx.y ? y : x;
  short* dh = blockIdx.y ? Yh : Xh;
  short* dl = blockIdx.y ? Yl : Xl;
  const size_t i = ((size_t)blockIdx.x * 256 + threadIdx.x) * 8;
  float4 a = *(const float4*)(src + i);
  float4 b = *(const float4*)(src + i + 4);
  float v[8] = {a.x, a.y, a.z, a.w, b.x, b.y, b.z, b.w};
  bf16x8 h, l;
#pragma unroll
  for (int j = 0; j < 8; ++j) {
    short hh, ll;
    splitbf(v[j], hh, ll);
    h[j] = hh;
    l[j] = ll;
  }
  *(bf16x8*)(dh + i) = h;
  *(bf16x8*)(dl + i) = l;
  if (blockIdx.y) {
    f16x8 m8;
#pragma unroll
    for (int j = 0; j < 8; ++j) m8[j] = (f16)v[j];
    *(f16x8*)(Ym + i) = m8;
  }
}

// ---------- gll-staged, double-buffered f16 GEMM (V-proj, out-GEMM) --------
#define GSTAGE(buf, kk)                                              \
  {                                                                  \
    _Pragma("unroll") for (int j = 0; j < 4; ++j) {                  \
      const int rowu = half + j * 16;                                \
      const int row = rowu + srow;                                   \
      const int slog = sslot ^ ((row >> 1) & 3);                     \
      GLL16(gsb + (size_t)(rb + row) * 512 + (kk) + slog * 8,        \
            &ldsb[buf][rowu][0]);                                    \
    }                                                                \
  }

template <typename OT>
__device__ __forceinline__ void gemm16_gll(const f16* __restrict__ A,
                                           const f16* __restrict__ WT,
                                           const float* __restrict__ bias,
                                           OT* __restrict__ C, int m0, int n0,
                                           f16 (*As)[128][32],
                                           f16 (*Bs)[128][32]) {
  const int tid = threadIdx.x;
  const int wv = tid >> 6, lane = tid & 63;
  const int wm = wv >> 1, wn = wv & 1;
  const int l15 = lane & 15, lg = lane >> 4;
  const int srow = lane >> 2, sslot = lane & 3;

  const f16* gsb = (wv < 2) ? A : WT;
  const int rb = (wv < 2) ? m0 : n0;
  f16(*ldsb)[128][32] = (wv < 2) ? As : Bs;
  const int half = (wv & 1) * 64;

  const f32x4 fz = {0.f, 0.f, 0.f, 0.f};
  f32x4 acc[4][4];
#pragma unroll
  for (int m = 0; m < 4; ++m)
#pragma unroll
    for (int n = 0; n < 4; ++n) acc[m][n] = fz;

  GSTAGE(0, 0);  // prologue
  int cur = 0;
  for (int k0 = 0; k0 < 512; k0 += 32) {
    __syncthreads();  // drains prefetch -> buf[cur] ready; prev reads done
    if (k0 < 480) GSTAGE(cur ^ 1, k0 + 32);  // in flight under compute
    f16x8 af[4], bf[4];
#pragma unroll
    for (int m = 0; m < 4; ++m) {
      const int r = wm * 64 + m * 16 + l15;
      af[m] = *(const f16x8*)&As[cur][r][(lg ^ ((r >> 1) & 3)) * 8];
    }
#pragma unroll
    for (int n = 0; n < 4; ++n) {
      const int r = wn * 64 + n * 16 + l15;
      bf[n] = *(const f16x8*)&Bs[cur][r][(lg ^ ((r >> 1) & 3)) * 8];
    }
#pragma unroll
    for (int m = 0; m < 4; ++m)
#pragma unroll
      for (int n = 0; n < 4; ++n) acc[m][n] = MFMA16(af[m], bf[n], acc[m][n]);
    cur ^= 1;
  }
#pragma unroll
  for (int n = 0; n < 4; ++n) {
    const int col = n0 + wn * 64 + n * 16 + l15;
    const float b = bias[col];
#pragma unroll
    for (int m = 0; m < 4; ++m) {
      const int row = m0 + wm * 64 + m * 16 + lg * 4;
#pragma unroll
      for (int r = 0; r < 4; ++r)
        C[(size_t)(row + r) * 512 + col] = (OT)(acc[m][n][r] + b);
    }
  }
}

__global__ __launch_bounds__(256) void k_gemm_out(const f16* __restrict__ Om,
                                                  const f16* __restrict__ owT,
                                                  const float* __restrict__ ob,
                                                  float* __restrict__ out) {
  __shared__ __align__(16) f16 As[2][128][32];
  __shared__ __align__(16) f16 Bs[2][128][32];
  const int lid = blockIdx.x + (blockIdx.y << 2);
  const int swz = ((lid & 7) << 5) + (lid >> 3);  // XCD-bijective (256=8x32)
  gemm16_gll<float>(Om, owT, ob, out, (swz >> 2) * 128, (swz & 3) * 128, As,
                    Bs);
}

// ---------------- merged projections: Q,K (split) + V (f16) ----------------
#define PSTAGE(buf, kk)                                             \
  {                                                                 \
    _Pragma("unroll") for (int j = 0; j < 8; ++j) {                 \
      const int row = j * 16 + srow;                                \
      const int slog = sslot ^ ((row >> 1) & 3);                    \
      GLL16(gsb + (size_t)(rb + row) * 512 + (kk) + slog * 8,       \
            &sm4[buf][wv][j * 16][0]);                              \
    }                                                               \
  }

__global__ __launch_bounds__(256) void k_proj(
    const short* __restrict__ Xh, const short* __restrict__ Xl,
    const short* __restrict__ Yh, const short* __restrict__ Yl,
    const f16* __restrict__ Ym, const short* __restrict__ qwh,
    const short* __restrict__ qwl, const short* __restrict__ kwh,
    const short* __restrict__ kwl, const f16* __restrict__ vwT,
    const float* __restrict__ qb, const float* __restrict__ kbias,
    const float* __restrict__ vb, short* __restrict__ Qh,
    short* __restrict__ Ql, short* __restrict__ Kh, short* __restrict__ Kl,
    f16* __restrict__ Vm, float* __restrict__ Kpart) {
  __shared__ __align__(16) short sm4[2][4][128][32];  // 64 KB (double-buffer)
  const int lid = blockIdx.x + (blockIdx.y << 2);
  const int swz = ((lid & 7) << 5) + (lid >> 3);  // XCD-bijective (256=8x32)
  const int nt = swz & 3, mt = swz >> 2;
  const int m0 = mt * 128, n0 = nt * 128;
  const int z = blockIdx.z;
  if (z == 2) {
    gemm16_gll<f16>(Ym, vwT, vb, Vm, m0, n0, (f16(*)[128][32]) & sm4[0][0][0][0],
                    (f16(*)[128][32]) & sm4[0][2][0][0]);
    return;
  }
  const short* Agh = z ? Yh : Xh;
  const short* Agl = z ? Yl : Xl;
  const short* Wh = z ? kwh : qwh;
  const short* Wl = z ? kwl : qwl;
  const float* bias = z ? kbias : qb;
  short* Ch = z ? Kh : Qh;
  short* Cl = z ? Kl : Ql;
  const float osc = z ? 1.f : (float)QPROJ_SCALE;  // Q pre-scaled for attn

  const int tid = threadIdx.x;
  const int wv = tid >> 6, lane = tid & 63;
  const int wm = wv >> 1, wn = wv & 1;
  const int l15 = lane & 15, lg = lane >> 4;
  const int srow = lane >> 2, sslot = lane & 3;

  // wave wv stages stream wv: 0=A-hi, 1=A-lo, 2=B-hi, 3=B-lo (8 KB each)
  const short* gsb = (wv == 0) ? Agh : (wv == 1) ? Agl : (wv == 2) ? Wh : Wl;
  const int rb = (wv < 2) ? m0 : n0;

  const f32x4 fz = {0.f, 0.f, 0.f, 0.f};
  f32x4 acc[4][4];
#pragma unroll
  for (int m = 0; m < 4; ++m)
#pragma unroll
    for (int n = 0; n < 4; ++n) acc[m][n] = fz;

  PSTAGE(0, 0);  // prologue
  int cur = 0;
  for (int k0 = 0; k0 < 512; k0 += 32) {
    __syncthreads();  // drains prefetch -> buf[cur] ready; prev reads done
    if (k0 < 480) PSTAGE(cur ^ 1, k0 + 32);  // in flight under compute
    bf16x8 afh[4], afl[4], bfh[4], bfl[4];
#pragma unroll
    for (int m = 0; m < 4; ++m) {
      const int r = wm * 64 + m * 16 + l15;
      const int sl = (lg ^ ((r >> 1) & 3)) * 8;
      afh[m] = *(const bf16x8*)&sm4[cur][0][r][sl];
      afl[m] = *(const bf16x8*)&sm4[cur][1][r][sl];
    }
#pragma unroll
    for (int n = 0; n < 4; ++n) {
      const int r = wn * 64 + n * 16 + l15;
      const int sl = (lg ^ ((r >> 1) & 3)) * 8;
      bfh[n] = *(const bf16x8*)&sm4[cur][2][r][sl];
      bfl[n] = *(const bf16x8*)&sm4[cur][3][r][sl];
    }
#pragma unroll
    for (int m = 0; m < 4; ++m)
#pragma unroll
      for (int n = 0; n < 4; ++n) {
        acc[m][n] = MFMAB16(afh[m], bfh[n], acc[m][n]);
        acc[m][n] = MFMAB16(afh[m], bfl[n], acc[m][n]);
        acc[m][n] = MFMAB16(afl[m], bfh[n], acc[m][n]);
      }
    cur ^= 1;
  }
  // epilogue: split-bf16 output (+ deterministic K column partial sums)
  float csum[4];
#pragma unroll
  for (int n = 0; n < 4; ++n) {
    const int col = n0 + wn * 64 + n * 16 + l15;
    const float b = bias[col];
    csum[n] = 16.f * b;
#pragma unroll
    for (int m = 0; m < 4; ++m) {
      const int row = m0 + wm * 64 + m * 16 + lg * 4;
#pragma unroll
      for (int r = 0; r < 4; ++r) {
        const float vraw = acc[m][n][r] + b;
        csum[n] += acc[m][n][r];
        short h, l;
        splitbf(vraw * osc, h, l);
        const size_t idx = (size_t)(row + r) * 512 + col;
        Ch[idx] = h;
        Cl[idx] = l;
      }
    }
  }
  if (z == 1) {
    // block-local column reduction (deterministic): 128 cols x 8 contributors
    float* cred = (float*)&sm4[0][0][0][0];
    __syncthreads();  // all waves done with LDS tiles
#pragma unroll
    for (int n = 0; n < 4; ++n)
      cred[(wn * 64 + n * 16 + l15) * 8 + wm * 4 + lg] = csum[n];
    __syncthreads();
    if (tid < 64) {
      float s = 0.f;
#pragma unroll
      for (int j = 0; j < 8; ++j)
        s += cred[tid * 8 + j] + cred[(tid + 64) * 8 + j];
      Kpart[((size_t)mt * 4 + nt) * 64 + tid] = s;  // mt == problem p
    }
  }
}

// ----------------------- V transpose (per problem) -------------------------
// Vm [8192][512] f16 -> Vt [64 p][64 dh][1024 k] f16.
__global__ __launch_bounds__(256) void k_vtr(const f16* __restrict__ Vm,
                                             f16* __restrict__ Vt) {
  const int p = blockIdx.y;
  const int j0 = blockIdx.x * 16;
  __shared__ f16 L[16][520];
  const int tid = threadIdx.x;
#pragma unroll
  for (int it = 0; it < 4; ++it) {
    int idx = it * 256 + tid;
    int row = idx >> 6, oct = idx & 63;
    *(f16x8*)&L[row][oct * 8] =
        *(const f16x8*)&Vm[(size_t)(p * 128 + j0 + row) * 512 + oct * 8];
  }
  __syncthreads();
#pragma unroll
  for (int it = 0; it < 4; ++it) {
    int idx = it * 256 + tid;
    int dh = idx >> 4, j = idx & 15;
    f16x8 v;
#pragma unroll
    for (int g = 0; g < 8; ++g) v[g] = L[j][g * 64 + dh];
    *(f16x8*)&Vt[((size_t)p * 64 + dh) * 1024 + (j0 + j) * 8] = v;
  }
}

// ------------------------------- attention ---------------------------------
// grid (64 problems, 16 q-tiles), 256 threads = 4 waves x 16 q = 64 q/block.
// Chunk = 32 keys, double-buffered LDS (24 KB) -> 4 blocks/CU, all 1024
// blocks co-resident, 16 waves/CU (4/SIMD). One barrier per chunk; chunk
// loop unrolled x2 (cb compile-time). setprio around MFMA. Bit-identical
// numerics to round 10 (same key order / MFMA partition).
#define LOADREG(cc)                                   \
  {                                                   \
    rh = *(const bf16x8*)(KhSrc + (cc) * 2048);       \
    rl = *(const bf16x8*)(KlSrc + (cc) * 2048);       \
    rv = *(const f16x8*)(VSrc + (cc) * 32);           \
  }
#define STOREBUF(b)                       \
  {                                       \
    *(bf16x8*)&KhS[b][skey][skslot] = rh; \
    *(bf16x8*)&KlS[b][skey][skslot] = rl; \
    *(f16x8*)&Vs[b][sdh][svslot] = rv;    \
  }

// one 32-key chunk with compile-time buffer index cb_
#define CHUNK(cb_, c_)                                                        \
  {                                                                           \
    __syncthreads();                                                          \
    if ((c_) < 31) STOREBUF((cb_) ^ 1); /* regs hold chunk c_+1 */            \
    if ((c_) < 30) LOADREG((c_) + 2);                                         \
    __builtin_amdgcn_s_setprio(1);                                            \
    _Pragma("unroll") for (int t = 0; t < 2; ++t) {                           \
      const int krow = t * 16 + l15;                                          \
      const int ksw = l15 & 7; /* krow&7 == l15&7 */                          \
      bf16x8 kh0 = *(const bf16x8*)&KhS[cb_][krow][(lg ^ ksw) * 8];           \
      bf16x8 kh1 = *(const bf16x8*)&KhS[cb_][krow][((4 + lg) ^ ksw) * 8];     \
      bf16x8 kl0 = *(const bf16x8*)&KlS[cb_][krow][(lg ^ ksw) * 8];           \
      bf16x8 kl1 = *(const bf16x8*)&KlS[cb_][krow][((4 + lg) ^ ksw) * 8];     \
      f32x4 a0 = fz;                                                          \
      a0 = MFMAB16(kh0, qh0, a0);                                             \
      a0 = MFMAB16(kh1, qh1, a0);                                             \
      a0 = MFMAB16(kh0, ql0, a0);                                             \
      a0 = MFMAB16(kl0, qh0, a0);                                             \
      a0 = MFMAB16(kh1, ql1, a0);                                             \
      a0 = MFMAB16(kl1, qh1, a0);                                             \
      f16x4 pf;                                                               \
      _Pragma("unroll") for (int r = 0; r < 4; ++r) {                         \
        float v = a0[r];                                                      \
        float e = (v > sm) ? EXPFN(v) : 0.f;                                  \
        pf[r] = (f16)e;                                                       \
      }                                                                       \
      od = MFMAPV(kones, pf, od);                                             \
      _Pragma("unroll") for (int d0 = 0; d0 < 4; ++d0) {                      \
        const int vrow = d0 * 16 + l15;                                       \
        const int vsw = l15 & 3; /* vrow&3 == l15&3 */                        \
        f16x4 va = *(const f16x4*)&Vs[cb_][vrow]                              \
                                      [(((t * 2 + (lg >> 1)) ^ vsw) * 8) +    \
                                       (lg & 1) * 4];                         \
        oac[d0] = MFMAPV(va, pf, oac[d0]);                                    \
      }                                                                       \
    }                                                                         \
    __builtin_amdgcn_s_setprio(0);                                            \
  }

__global__ __launch_bounds__(256, 4) void k_attn(
    const short* __restrict__ Qh, const short* __restrict__ Ql,
    const short* __restrict__ Kh, const short* __restrict__ Kl,
    const f16* __restrict__ Vt, const float* __restrict__ Kpart,
    f16* __restrict__ Om) {
  constexpr int S = 1024, DH = 64;
  const int p = blockIdx.x;
  const int qt = blockIdx.y;  // 0..15, 64 q per block
  const size_t pb = (size_t)p * S * DH;
  const short* Qhp = Qh + pb;
  const short* Qlp = Ql + pb;
  const short* Khp = Kh + pb;
  const short* Klp = Kl + pb;
  const f16* Vtp = Vt + pb;  // [64 dh][1024 k]
  f16* Op = Om + pb;

  const int tid = threadIdx.x;
  const int w = tid >> 6, lane = tid & 63;
  const int l15 = lane & 15, lg = lane >> 4;

  __shared__ __align__(16) short KhS[2][32][64];  // [key][dh]
  __shared__ __align__(16) short KlS[2][32][64];
  __shared__ __align__(16) f16 Vs[2][64][32];  // [dh][key]; 24 KB total

  // staging: K planes: 1 bf16x8 per thread; V: 1 f16x8 per thread
  const int skey = tid >> 3;                     // 0..31 key
  const int sk8 = tid & 7;                       // 8 slots of 16B
  const int skslot = (sk8 ^ (skey & 7)) * 8;
  const int sdh = tid >> 2;                      // 0..63 dh
  const int sv4 = tid & 3;                       // 4 slots of 16B
  const int svslot = (sv4 ^ (sdh & 3)) * 8;
  const short* KhSrc = Khp + skey * 64 + sk8 * 8;
  const short* KlSrc = Klp + skey * 64 + sk8 * 8;
  const f16* VSrc = Vtp + (size_t)sdh * 1024 + sv4 * 8;

  bf16x8 rh, rl;
  f16x8 rv;
  LOADREG(0);
  STOREBUF(0);  // visible to all after iter-0 barrier
  LOADREG(1);

  // this wave's 16-q group (Q pre-scaled by QPROJ_SCALE)
  const int qrow = qt * 64 + w * 16;
  const size_t qo = (size_t)(qrow + l15) * DH + lg * 8;
  bf16x8 qh0 = *(const bf16x8*)(Qhp + qo);
  bf16x8 ql0 = *(const bf16x8*)(Qlp + qo);
  bf16x8 qh1 = *(const bf16x8*)(Qhp + qo + 32);
  bf16x8 ql1 = *(const bf16x8*)(Qlp + qo + 32);

  // threshold: mean_q = (Qscaled_q . Ksum) / 1024, Ksum = sum of 4 partials
  const float* kp = Kpart + (size_t)p * 256;
  float km0[8], km1[8];
#pragma unroll
  for (int j = 0; j < 8; ++j) { km0[j] = 0.f; km1[j] = 0.f; }
#pragma unroll
  for (int pt = 0; pt < 4; ++pt) {
    const float* bb = kp + pt * 64;
#pragma unroll
    for (int j = 0; j < 8; ++j) {
      km0[j] += bb[lg * 8 + j];
      km1[j] += bb[32 + lg * 8 + j];
    }
  }
  float sm = 0.f;
#pragma unroll
  for (int j = 0; j < 8; ++j) {
    sm += (b2f(qh0[j]) + b2f(ql0[j])) * km0[j] +
          (b2f(qh1[j]) + b2f(ql1[j])) * km1[j];
  }
  sm += __shfl_xor(sm, 16);
  sm += __shfl_xor(sm, 32);
  sm *= (1.f / 1024.f);

  const f32x4 fz = {0.f, 0.f, 0.f, 0.f};
  const f16x4 kones = {(f16)1.f, (f16)1.f, (f16)1.f, (f16)1.f};
  f32x4 oac[4];
#pragma unroll
  for (int d = 0; d < 4; ++d) oac[d] = fz;
  f32x4 od = fz;

  for (int cc = 0; cc < 32; cc += 2) {
    CHUNK(0, cc);
    CHUNK(1, cc + 1);
  }

  const float inv = 1.f / od[0];  // all 4 regs equal (sum over all k)
#pragma unroll
  for (int d0 = 0; d0 < 4; ++d0) {
    f16x4 o0;
#pragma unroll
    for (int r = 0; r < 4; ++r) o0[r] = (f16)(oac[d0][r] * inv);
    *(f16x4*)&Op[(size_t)(qrow + l15) * DH + d0 * 16 + lg * 4] = o0;
  }
}

// ------------------------------- launcher ----------------------------------
extern "C" void kernel_launch(void* const* d_in, const int* in_sizes, int n_in,
                              void* d_out, int out_size, void* d_ws,
                              size_t ws_size, hipStream_t stream) {
  const float* x = (const float*)d_in[0];
  const float* y = (const float*)d_in[1];
  const float* qw = (const float*)d_in[2];
  const float* qb = (const float*)d_in[3];
  const float* kw = (const float*)d_in[4];
  const float* kbias = (const float*)d_in[5];
  const float* vw = (const float*)d_in[6];
  const float* vb = (const float*)d_in[7];
  const float* ow = (const float*)d_in[8];
  const float* ob = (const float*)d_in[9];
  float* out = (float*)d_out;

  char* ws = (char*)d_ws;
  const size_t WT_B = 512ull * 512 * 2;    // 512 KB
  const size_t MAT_B = 8192ull * 512 * 2;  // 8 MB
  short* qwhT = (short*)(ws + 0 * WT_B);
  short* qwlT = (short*)(ws + 1 * WT_B);
  short* kwhT = (short*)(ws + 2 * WT_B);
  short* kwlT = (short*)(ws + 3 * WT_B);
  f16* vwT = (f16*)(ws + 4 * WT_B);
  f16* owT = (f16*)(ws + 5 * WT_B);
  char* m = ws + 6 * WT_B;
  short* Qh = (short*)(m + 0 * MAT_B);
  short* Ql = (short*)(m + 1 * MAT_B);
  short* Kh = (short*)(m + 2 * MAT_B);
  short* Kl = (short*)(m + 3 * MAT_B);
  f16* Vm = (f16*)(m + 4 * MAT_B);
  short* Xh = (short*)(m + 5 * MAT_B);
  short* Xl = (short*)(m + 6 * MAT_B);
  short* Yh = (short*)(m + 7 * MAT_B);
  short* Yl = (short*)(m + 8 * MAT_B);
  f16* Ym = (f16*)(m + 9 * MAT_B);
  float* Kpart = (float*)(m + 10 * MAT_B);  // 64 KB; total ~83.1 MB
  // dead-buffer aliases (stream order makes these safe):
  f16* Vtr = (f16*)Xh;  // k_vtr runs after k_proj (Xh consumed)
  f16* Om = (f16*)Yh;   // k_attn runs after k_proj (Yh consumed)

  hipLaunchKernelGGL(k_wt, dim3(16, 16, 4), dim3(32, 8), 0, stream, qw, kw, vw,
                     ow, qwhT, qwlT, kwhT, kwlT, vwT, owT);
  hipLaunchKernelGGL(k_split, dim3(2048, 2), dim3(256), 0, stream, x, y, Xh,
                     Xl, Yh, Yl, Ym);
  hipLaunchKernelGGL(k_proj, dim3(4, 64, 3), dim3(256), 0, stream, Xh, Xl, Yh,
                     Yl, Ym, qwhT, qwlT, kwhT, kwlT, vwT, qb, kbias, vb, Qh,
                     Ql, Kh, Kl, Vm, Kpart);
  hipLaunchKernelGGL(k_vtr, dim3(8, 64), dim3(256), 0, stream, Vm, Vtr);
  hipLaunchKernelGGL(k_attn, dim3(64, 16), dim3(256), 0, stream, Qh, Ql, Kh,
                     Kl, Vtr, Kpart, Om);
  hipLaunchKernelGGL(k_gemm_out, dim3(4, 64), dim3(256), 0, stream, Om, owT,
                     ob, out);
}

// Round 12
// 118.411 us; speedup vs baseline: 1.1167x; 1.1167x over previous
//
#include <hip/hip_runtime.h>
#include <hip/hip_bf16.h>
#include <hip/hip_fp16.h>

// ---------------------------------------------------------------------------
// Multihead attention with flat-reshape head split + mean-threshold mask.
//   B=8 S=1024 D=512 H=8 -> 64 independent attention problems of (1024 x 64);
//   problem (h,b) = 128 consecutive rows of the 8192x512 projected matrix
//   reinterpreted as 1024x64.
// Precision: Q/K path 3-term bf16 split -> fp32-accurate scores. V/P/O fp16.
// Round-12 (k_attn only):
//   * REVERT to round-9 geometry (best measured: 512 thr / 8 waves / 16 q
//     per wave / 64-key chunks). Round-10 (q-reuse) and round-11 (occupancy)
//     were nulls/regressions -> limiter is in-order issue stalls: serial
//     6-link MFMA accumulator chains + dependent exp block.
//   * ILP restructure of the chunk body: batched phases (4 QK tiles -> V
//     preload -> exps -> PVs) and 2-way chain split per tile (k-halves into
//     s1/s2, summed) -> 8 independent 3-link QK chains per chunk.
//   * Numerics: fp32 reassociation only (~1e-7 on scores) -> absmax ~3.4e-3.
// ---------------------------------------------------------------------------

typedef _Float16 f16;
typedef __attribute__((ext_vector_type(4))) _Float16 f16x4;
typedef __attribute__((ext_vector_type(8))) _Float16 f16x8;
typedef __attribute__((ext_vector_type(8))) short bf16x8;
typedef __attribute__((ext_vector_type(4))) float f32x4;

#define MFMA16(a, b, c) __builtin_amdgcn_mfma_f32_16x16x32_f16((a), (b), (c), 0, 0, 0)
#define MFMAB16(a, b, c) __builtin_amdgcn_mfma_f32_16x16x32_bf16((a), (b), (c), 0, 0, 0)
#define MFMAPV(a, b, c) __builtin_amdgcn_mfma_f32_16x16x16f16((a), (b), (c), 0, 0, 0)

#if defined(__has_builtin) && __has_builtin(__builtin_amdgcn_exp2f)
#define EXPFN(x) __builtin_amdgcn_exp2f(x)
#define QPROJ_SCALE (0.04419417382415922f * 1.4426950408889634f)
#else
#define EXPFN(x) __expf(x)
#define QPROJ_SCALE 0.04419417382415922f
#endif

// async global->LDS, 16B per lane; LDS dst = wave-uniform base + lane*16
#define GLL16(gp, lp)                                       \
  __builtin_amdgcn_global_load_lds(                         \
      (const __attribute__((address_space(1))) void*)(gp),  \
      (__attribute__((address_space(3))) void*)(lp), 16, 0, 0)

__device__ __forceinline__ float b2f(short s) {
  return __uint_as_float(((unsigned)(unsigned short)s) << 16);
}

__device__ __forceinline__ void splitbf(float v, short& h, short& l) {
  unsigned short hu = __bfloat16_as_ushort(__float2bfloat16(v));
  h = (short)hu;
  float hf = __uint_as_float(((unsigned)hu) << 16);
  l = (short)__bfloat16_as_ushort(__float2bfloat16(v - hf));
}

// --------------------------- weight transpose+convert ----------------------
__global__ void k_wt(const float* __restrict__ w0, const float* __restrict__ w1,
                     const float* __restrict__ w2, const float* __restrict__ w3,
                     short* __restrict__ qh, short* __restrict__ ql,
                     short* __restrict__ kh, short* __restrict__ kl,
                     f16* __restrict__ vt, f16* __restrict__ ot) {
  const float* W;
  switch (blockIdx.z) {
    case 0: W = w0; break;
    case 1: W = w1; break;
    case 2: W = w2; break;
    default: W = w3; break;
  }
  __shared__ float t[32][33];
  int bx = blockIdx.x, by = blockIdx.y;
  int tx = threadIdx.x, ty = threadIdx.y;  // 32 x 8
#pragma unroll
  for (int i = 0; i < 32; i += 8)
    t[ty + i][tx] = W[(size_t)(by * 32 + ty + i) * 512 + bx * 32 + tx];
  __syncthreads();
#pragma unroll
  for (int i = 0; i < 32; i += 8) {
    size_t idx = (size_t)(bx * 32 + ty + i) * 512 + by * 32 + tx;
    float v = t[tx][ty + i];
    if (blockIdx.z < 2) {
      short h, l;
      splitbf(v, h, l);
      if (blockIdx.z == 0) { qh[idx] = h; ql[idx] = l; }
      else { kh[idx] = h; kl[idx] = l; }
    } else {
      if (blockIdx.z == 2) vt[idx] = (f16)v;
      else ot[idx] = (f16)v;
    }
  }
}

// ------------------ input split (x,y -> bf16 hi/lo; y -> f16) --------------
__global__ __launch_bounds__(256) void k_split(
    const float* __restrict__ x, const float* __restrict__ y,
    short* __restrict__ Xh, short* __restrict__ Xl, short* __restrict__ Yh,
    short* __restrict__ Yl, f16* __restrict__ Ym) {
  const float* src = blockIdx.y ? y : x;
  short* dh = blockIdx.y ? Yh : Xh;
  short* dl = blockIdx.y ? Yl : Xl;
  const size_t i = ((size_t)blockIdx.x * 256 + threadIdx.x) * 8;
  float4 a = *(const float4*)(src + i);
  float4 b = *(const float4*)(src + i + 4);
  float v[8] = {a.x, a.y, a.z, a.w, b.x, b.y, b.z, b.w};
  bf16x8 h, l;
#pragma unroll
  for (int j = 0; j < 8; ++j) {
    short hh, ll;
    splitbf(v[j], hh, ll);
    h[j] = hh;
    l[j] = ll;
  }
  *(bf16x8*)(dh + i) = h;
  *(bf16x8*)(dl + i) = l;
  if (blockIdx.y) {
    f16x8 m8;
#pragma unroll
    for (int j = 0; j < 8; ++j) m8[j] = (f16)v[j];
    *(f16x8*)(Ym + i) = m8;
  }
}

// ---------- gll-staged, double-buffered f16 GEMM (V-proj, out-GEMM) --------
#define GSTAGE(buf, kk)                                              \
  {                                                                  \
    _Pragma("unroll") for (int j = 0; j < 4; ++j) {                  \
      const int rowu = half + j * 16;                                \
      const int row = rowu + srow;                                   \
      const int slog = sslot ^ ((row >> 1) & 3);                     \
      GLL16(gsb + (size_t)(rb + row) * 512 + (kk) + slog * 8,        \
            &ldsb[buf][rowu][0]);                                    \
    }                                                                \
  }

template <typename OT>
__device__ __forceinline__ void gemm16_gll(const f16* __restrict__ A,
                                           const f16* __restrict__ WT,
                                           const float* __restrict__ bias,
                                           OT* __restrict__ C, int m0, int n0,
                                           f16 (*As)[128][32],
                                           f16 (*Bs)[128][32]) {
  const int tid = threadIdx.x;
  const int wv = tid >> 6, lane = tid & 63;
  const int wm = wv >> 1, wn = wv & 1;
  const int l15 = lane & 15, lg = lane >> 4;
  const int srow = lane >> 2, sslot = lane & 3;

  const f16* gsb = (wv < 2) ? A : WT;
  const int rb = (wv < 2) ? m0 : n0;
  f16(*ldsb)[128][32] = (wv < 2) ? As : Bs;
  const int half = (wv & 1) * 64;

  const f32x4 fz = {0.f, 0.f, 0.f, 0.f};
  f32x4 acc[4][4];
#pragma unroll
  for (int m = 0; m < 4; ++m)
#pragma unroll
    for (int n = 0; n < 4; ++n) acc[m][n] = fz;

  GSTAGE(0, 0);  // prologue
  int cur = 0;
  for (int k0 = 0; k0 < 512; k0 += 32) {
    __syncthreads();  // drains prefetch -> buf[cur] ready; prev reads done
    if (k0 < 480) GSTAGE(cur ^ 1, k0 + 32);  // in flight under compute
    f16x8 af[4], bf[4];
#pragma unroll
    for (int m = 0; m < 4; ++m) {
      const int r = wm * 64 + m * 16 + l15;
      af[m] = *(const f16x8*)&As[cur][r][(lg ^ ((r >> 1) & 3)) * 8];
    }
#pragma unroll
    for (int n = 0; n < 4; ++n) {
      const int r = wn * 64 + n * 16 + l15;
      bf[n] = *(const f16x8*)&Bs[cur][r][(lg ^ ((r >> 1) & 3)) * 8];
    }
#pragma unroll
    for (int m = 0; m < 4; ++m)
#pragma unroll
      for (int n = 0; n < 4; ++n) acc[m][n] = MFMA16(af[m], bf[n], acc[m][n]);
    cur ^= 1;
  }
#pragma unroll
  for (int n = 0; n < 4; ++n) {
    const int col = n0 + wn * 64 + n * 16 + l15;
    const float b = bias[col];
#pragma unroll
    for (int m = 0; m < 4; ++m) {
      const int row = m0 + wm * 64 + m * 16 + lg * 4;
#pragma unroll
      for (int r = 0; r < 4; ++r)
        C[(size_t)(row + r) * 512 + col] = (OT)(acc[m][n][r] + b);
    }
  }
}

__global__ __launch_bounds__(256) void k_gemm_out(const f16* __restrict__ Om,
                                                  const f16* __restrict__ owT,
                                                  const float* __restrict__ ob,
                                                  float* __restrict__ out) {
  __shared__ __align__(16) f16 As[2][128][32];
  __shared__ __align__(16) f16 Bs[2][128][32];
  const int lid = blockIdx.x + (blockIdx.y << 2);
  const int swz = ((lid & 7) << 5) + (lid >> 3);  // XCD-bijective (256=8x32)
  gemm16_gll<float>(Om, owT, ob, out, (swz >> 2) * 128, (swz & 3) * 128, As,
                    Bs);
}

// ---------------- merged projections: Q,K (split) + V (f16) ----------------
#define PSTAGE(buf, kk)                                             \
  {                                                                 \
    _Pragma("unroll") for (int j = 0; j < 8; ++j) {                 \
      const int row = j * 16 + srow;                                \
      const int slog = sslot ^ ((row >> 1) & 3);                    \
      GLL16(gsb + (size_t)(rb + row) * 512 + (kk) + slog * 8,       \
            &sm4[buf][wv][j * 16][0]);                              \
    }                                                               \
  }

__global__ __launch_bounds__(256) void k_proj(
    const short* __restrict__ Xh, const short* __restrict__ Xl,
    const short* __restrict__ Yh, const short* __restrict__ Yl,
    const f16* __restrict__ Ym, const short* __restrict__ qwh,
    const short* __restrict__ qwl, const short* __restrict__ kwh,
    const short* __restrict__ kwl, const f16* __restrict__ vwT,
    const float* __restrict__ qb, const float* __restrict__ kbias,
    const float* __restrict__ vb, short* __restrict__ Qh,
    short* __restrict__ Ql, short* __restrict__ Kh, short* __restrict__ Kl,
    f16* __restrict__ Vm, float* __restrict__ Kpart) {
  __shared__ __align__(16) short sm4[2][4][128][32];  // 64 KB (double-buffer)
  const int lid = blockIdx.x + (blockIdx.y << 2);
  const int swz = ((lid & 7) << 5) + (lid >> 3);  // XCD-bijective (256=8x32)
  const int nt = swz & 3, mt = swz >> 2;
  const int m0 = mt * 128, n0 = nt * 128;
  const int z = blockIdx.z;
  if (z == 2) {
    gemm16_gll<f16>(Ym, vwT, vb, Vm, m0, n0, (f16(*)[128][32]) & sm4[0][0][0][0],
                    (f16(*)[128][32]) & sm4[0][2][0][0]);
    return;
  }
  const short* Agh = z ? Yh : Xh;
  const short* Agl = z ? Yl : Xl;
  const short* Wh = z ? kwh : qwh;
  const short* Wl = z ? kwl : qwl;
  const float* bias = z ? kbias : qb;
  short* Ch = z ? Kh : Qh;
  short* Cl = z ? Kl : Ql;
  const float osc = z ? 1.f : (float)QPROJ_SCALE;  // Q pre-scaled for attn

  const int tid = threadIdx.x;
  const int wv = tid >> 6, lane = tid & 63;
  const int wm = wv >> 1, wn = wv & 1;
  const int l15 = lane & 15, lg = lane >> 4;
  const int srow = lane >> 2, sslot = lane & 3;

  // wave wv stages stream wv: 0=A-hi, 1=A-lo, 2=B-hi, 3=B-lo (8 KB each)
  const short* gsb = (wv == 0) ? Agh : (wv == 1) ? Agl : (wv == 2) ? Wh : Wl;
  const int rb = (wv < 2) ? m0 : n0;

  const f32x4 fz = {0.f, 0.f, 0.f, 0.f};
  f32x4 acc[4][4];
#pragma unroll
  for (int m = 0; m < 4; ++m)
#pragma unroll
    for (int n = 0; n < 4; ++n) acc[m][n] = fz;

  PSTAGE(0, 0);  // prologue
  int cur = 0;
  for (int k0 = 0; k0 < 512; k0 += 32) {
    __syncthreads();  // drains prefetch -> buf[cur] ready; prev reads done
    if (k0 < 480) PSTAGE(cur ^ 1, k0 + 32);  // in flight under compute
    bf16x8 afh[4], afl[4], bfh[4], bfl[4];
#pragma unroll
    for (int m = 0; m < 4; ++m) {
      const int r = wm * 64 + m * 16 + l15;
      const int sl = (lg ^ ((r >> 1) & 3)) * 8;
      afh[m] = *(const bf16x8*)&sm4[cur][0][r][sl];
      afl[m] = *(const bf16x8*)&sm4[cur][1][r][sl];
    }
#pragma unroll
    for (int n = 0; n < 4; ++n) {
      const int r = wn * 64 + n * 16 + l15;
      const int sl = (lg ^ ((r >> 1) & 3)) * 8;
      bfh[n] = *(const bf16x8*)&sm4[cur][2][r][sl];
      bfl[n] = *(const bf16x8*)&sm4[cur][3][r][sl];
    }
#pragma unroll
    for (int m = 0; m < 4; ++m)
#pragma unroll
      for (int n = 0; n < 4; ++n) {
        acc[m][n] = MFMAB16(afh[m], bfh[n], acc[m][n]);
        acc[m][n] = MFMAB16(afh[m], bfl[n], acc[m][n]);
        acc[m][n] = MFMAB16(afl[m], bfh[n], acc[m][n]);
      }
    cur ^= 1;
  }
  // epilogue: split-bf16 output (+ deterministic K column partial sums)
  float csum[4];
#pragma unroll
  for (int n = 0; n < 4; ++n) {
    const int col = n0 + wn * 64 + n * 16 + l15;
    const float b = bias[col];
    csum[n] = 16.f * b;
#pragma unroll
    for (int m = 0; m < 4; ++m) {
      const int row = m0 + wm * 64 + m * 16 + lg * 4;
#pragma unroll
      for (int r = 0; r < 4; ++r) {
        const float vraw = acc[m][n][r] + b;
        csum[n] += acc[m][n][r];
        short h, l;
        splitbf(vraw * osc, h, l);
        const size_t idx = (size_t)(row + r) * 512 + col;
        Ch[idx] = h;
        Cl[idx] = l;
      }
    }
  }
  if (z == 1) {
    // block-local column reduction (deterministic): 128 cols x 8 contributors
    float* cred = (float*)&sm4[0][0][0][0];
    __syncthreads();  // all waves done with LDS tiles
#pragma unroll
    for (int n = 0; n < 4; ++n)
      cred[(wn * 64 + n * 16 + l15) * 8 + wm * 4 + lg] = csum[n];
    __syncthreads();
    if (tid < 64) {
      float s = 0.f;
#pragma unroll
      for (int j = 0; j < 8; ++j)
        s += cred[tid * 8 + j] + cred[(tid + 64) * 8 + j];
      Kpart[((size_t)mt * 4 + nt) * 64 + tid] = s;  // mt == problem p
    }
  }
}

// ----------------------- V transpose (per problem) -------------------------
// Vm [8192][512] f16 -> Vt [64 p][64 dh][1024 k] f16.
__global__ __launch_bounds__(256) void k_vtr(const f16* __restrict__ Vm,
                                             f16* __restrict__ Vt) {
  const int p = blockIdx.y;
  const int j0 = blockIdx.x * 16;
  __shared__ f16 L[16][520];
  const int tid = threadIdx.x;
#pragma unroll
  for (int it = 0; it < 4; ++it) {
    int idx = it * 256 + tid;
    int row = idx >> 6, oct = idx & 63;
    *(f16x8*)&L[row][oct * 8] =
        *(const f16x8*)&Vm[(size_t)(p * 128 + j0 + row) * 512 + oct * 8];
  }
  __syncthreads();
#pragma unroll
  for (int it = 0; it < 4; ++it) {
    int idx = it * 256 + tid;
    int dh = idx >> 4, j = idx & 15;
    f16x8 v;
#pragma unroll
    for (int g = 0; g < 8; ++g) v[g] = L[j][g * 64 + dh];
    *(f16x8*)&Vt[((size_t)p * 64 + dh) * 1024 + (j0 + j) * 8] = v;
  }
}

// ------------------------------- attention ---------------------------------
// grid (64 problems, 8 q-tiles), 512 threads = 8 waves, ONE 16-q group/wave.
// 64-key chunks, double-buffered LDS (48 KB), one barrier per chunk.
// Chunk body is phase-batched for ILP: 4 QK tiles (2 independent 3-chains
// each) -> V-frag preload -> 16 masked exps -> 20 PV MFMAs (5 indep chains).
#define LOADREG(cc)                              \
  {                                              \
    rh = *(const bf16x8*)(KhSrc + (cc) * 4096);  \
    rl = *(const bf16x8*)(KlSrc + (cc) * 4096);  \
    rv = *(const f16x8*)(VSrc + (cc) * 64);      \
  }
#define STOREBUF(b)                      \
  {                                      \
    *(bf16x8*)&KhS[b][skey][sslot] = rh; \
    *(bf16x8*)&KlS[b][skey][sslot] = rl; \
    *(f16x8*)&Vs[b][skey][sslot] = rv;   \
  }

// one 64-key chunk with compile-time buffer index cb_
#define CHUNK(cb_, c_)                                                        \
  {                                                                           \
    __syncthreads();                                                          \
    if ((c_) < 15) STOREBUF((cb_) ^ 1); /* regs hold chunk c_+1 */            \
    if ((c_) < 14) LOADREG((c_) + 2);                                         \
    __builtin_amdgcn_s_setprio(1);                                            \
    f32x4 aa[4];                                                              \
    _Pragma("unroll") for (int t = 0; t < 4; ++t) {                           \
      const int krow = t * 16 + l15;                                          \
      const int ksw = l15 & 7; /* krow&7 == l15&7 */                          \
      bf16x8 kh0 = *(const bf16x8*)&KhS[cb_][krow][(lg ^ ksw) * 8];           \
      bf16x8 kh1 = *(const bf16x8*)&KhS[cb_][krow][((4 + lg) ^ ksw) * 8];     \
      bf16x8 kl0 = *(const bf16x8*)&KlS[cb_][krow][(lg ^ ksw) * 8];           \
      bf16x8 kl1 = *(const bf16x8*)&KlS[cb_][krow][((4 + lg) ^ ksw) * 8];     \
      f32x4 s1 = fz, s2 = fz;                                                 \
      s1 = MFMAB16(kh0, qh0, s1);                                             \
      s2 = MFMAB16(kh1, qh1, s2);                                             \
      s1 = MFMAB16(kl0, qh0, s1);                                             \
      s2 = MFMAB16(kl1, qh1, s2);                                             \
      s1 = MFMAB16(kh0, ql0, s1);                                             \
      s2 = MFMAB16(kh1, ql1, s2);                                             \
      aa[t] = s1 + s2;                                                        \
    }                                                                         \
    f16x4 va[4][4];                                                           \
    _Pragma("unroll") for (int d0 = 0; d0 < 4; ++d0) {                        \
      const int vrow = d0 * 16 + l15;                                         \
      const int vsw = l15 & 7;                                                \
      _Pragma("unroll") for (int t = 0; t < 4; ++t)                           \
        va[d0][t] = *(const f16x4*)&Vs[cb_][vrow]                             \
                        [(((t * 2 + (lg >> 1)) ^ vsw) * 8) + (lg & 1) * 4];   \
    }                                                                         \
    f16x4 pf[4];                                                              \
    _Pragma("unroll") for (int t = 0; t < 4; ++t)                             \
      _Pragma("unroll") for (int r = 0; r < 4; ++r) {                         \
        float v = aa[t][r];                                                   \
        pf[t][r] = (f16)((v > sm) ? EXPFN(v) : 0.f);                          \
      }                                                                       \
    _Pragma("unroll") for (int t = 0; t < 4; ++t) {                           \
      od = MFMAPV(kones, pf[t], od);                                          \
      _Pragma("unroll") for (int d0 = 0; d0 < 4; ++d0)                        \
        oac[d0] = MFMAPV(va[d0][t], pf[t], oac[d0]);                          \
    }                                                                         \
    __builtin_amdgcn_s_setprio(0);                                            \
  }

__global__ __launch_bounds__(512, 4) void k_attn(
    const short* __restrict__ Qh, const short* __restrict__ Ql,
    const short* __restrict__ Kh, const short* __restrict__ Kl,
    const f16* __restrict__ Vt, const float* __restrict__ Kpart,
    f16* __restrict__ Om) {
  constexpr int S = 1024, DH = 64;
  const int p = blockIdx.x;
  const int qt = blockIdx.y;
  const size_t pb = (size_t)p * S * DH;
  const short* Qhp = Qh + pb;
  const short* Qlp = Ql + pb;
  const short* Khp = Kh + pb;
  const short* Klp = Kl + pb;
  const f16* Vtp = Vt + pb;  // [64 dh][1024 k]
  f16* Op = Om + pb;

  const int tid = threadIdx.x;
  const int w = tid >> 6, lane = tid & 63;
  const int l15 = lane & 15, lg = lane >> 4;

  __shared__ __align__(16) short KhS[2][64][64];
  __shared__ __align__(16) short KlS[2][64][64];
  __shared__ __align__(16) f16 Vs[2][64][64];  // 48 KB total

  const int skey = tid >> 3;
  const int slot8 = tid & 7;
  const int sslot = (slot8 ^ (skey & 7)) * 8;
  const short* KhSrc = Khp + skey * 64 + slot8 * 8;
  const short* KlSrc = Klp + skey * 64 + slot8 * 8;
  const f16* VSrc = Vtp + (size_t)skey * 1024 + slot8 * 8;

  bf16x8 rh, rl;
  f16x8 rv;
  LOADREG(0);
  STOREBUF(0);  // visible to all after iter-0 barrier
  LOADREG(1);

  // this wave's 16-q group (Q pre-scaled by QPROJ_SCALE)
  const int qrow = qt * 128 + w * 16;
  const size_t qo = (size_t)(qrow + l15) * DH + lg * 8;
  bf16x8 qh0 = *(const bf16x8*)(Qhp + qo);
  bf16x8 ql0 = *(const bf16x8*)(Qlp + qo);
  bf16x8 qh1 = *(const bf16x8*)(Qhp + qo + 32);
  bf16x8 ql1 = *(const bf16x8*)(Qlp + qo + 32);

  // threshold: mean_q = (Qscaled_q . Ksum) / 1024, Ksum = sum of 4 partials
  const float* kp = Kpart + (size_t)p * 256;
  float km0[8], km1[8];
#pragma unroll
  for (int j = 0; j < 8; ++j) { km0[j] = 0.f; km1[j] = 0.f; }
#pragma unroll
  for (int pt = 0; pt < 4; ++pt) {
    const float* bb = kp + pt * 64;
#pragma unroll
    for (int j = 0; j < 8; ++j) {
      km0[j] += bb[lg * 8 + j];
      km1[j] += bb[32 + lg * 8 + j];
    }
  }
  float sm = 0.f;
#pragma unroll
  for (int j = 0; j < 8; ++j) {
    sm += (b2f(qh0[j]) + b2f(ql0[j])) * km0[j] +
          (b2f(qh1[j]) + b2f(ql1[j])) * km1[j];
  }
  sm += __shfl_xor(sm, 16);
  sm += __shfl_xor(sm, 32);
  sm *= (1.f / 1024.f);

  const f32x4 fz = {0.f, 0.f, 0.f, 0.f};
  const f16x4 kones = {(f16)1.f, (f16)1.f, (f16)1.f, (f16)1.f};
  f32x4 oac[4];
#pragma unroll
  for (int d = 0; d < 4; ++d) oac[d] = fz;
  f32x4 od = fz;

  for (int cc = 0; cc < 16; cc += 2) {
    CHUNK(0, cc);
    CHUNK(1, cc + 1);
  }

  const float inv = 1.f / od[0];  // all 4 regs equal (sum over all k)
#pragma unroll
  for (int d0 = 0; d0 < 4; ++d0) {
    f16x4 o0;
#pragma unroll
    for (int r = 0; r < 4; ++r) o0[r] = (f16)(oac[d0][r] * inv);
    *(f16x4*)&Op[(size_t)(qrow + l15) * DH + d0 * 16 + lg * 4] = o0;
  }
}

// ------------------------------- launcher ----------------------------------
extern "C" void kernel_launch(void* const* d_in, const int* in_sizes, int n_in,
                              void* d_out, int out_size, void* d_ws,
                              size_t ws_size, hipStream_t stream) {
  const float* x = (const float*)d_in[0];
  const float* y = (const float*)d_in[1];
  const float* qw = (const float*)d_in[2];
  const float* qb = (const float*)d_in[3];
  const float* kw = (const float*)d_in[4];
  const float* kbias = (const float*)d_in[5];
  const float* vw = (const float*)d_in[6];
  const float* vb = (const float*)d_in[7];
  const float* ow = (const float*)d_in[8];
  const float* ob = (const float*)d_in[9];
  float* out = (float*)d_out;

  char* ws = (char*)d_ws;
  const size_t WT_B = 512ull * 512 * 2;    // 512 KB
  const size_t MAT_B = 8192ull * 512 * 2;  // 8 MB
  short* qwhT = (short*)(ws + 0 * WT_B);
  short* qwlT = (short*)(ws + 1 * WT_B);
  short* kwhT = (short*)(ws + 2 * WT_B);
  short* kwlT = (short*)(ws + 3 * WT_B);
  f16* vwT = (f16*)(ws + 4 * WT_B);
  f16* owT = (f16*)(ws + 5 * WT_B);
  char* m = ws + 6 * WT_B;
  short* Qh = (short*)(m + 0 * MAT_B);
  short* Ql = (short*)(m + 1 * MAT_B);
  short* Kh = (short*)(m + 2 * MAT_B);
  short* Kl = (short*)(m + 3 * MAT_B);
  f16* Vm = (f16*)(m + 4 * MAT_B);
  short* Xh = (short*)(m + 5 * MAT_B);
  short* Xl = (short*)(m + 6 * MAT_B);
  short* Yh = (short*)(m + 7 * MAT_B);
  short* Yl = (short*)(m + 8 * MAT_B);
  f16* Ym = (f16*)(m + 9 * MAT_B);
  float* Kpart = (float*)(m + 10 * MAT_B);  // 64 KB; total ~83.1 MB
  // dead-buffer aliases (stream order makes these safe):
  f16* Vtr = (f16*)Xh;  // k_vtr runs after k_proj (Xh consumed)
  f16* Om = (f16*)Yh;   // k_attn runs after k_proj (Yh consumed)

  hipLaunchKernelGGL(k_wt, dim3(16, 16, 4), dim3(32, 8), 0, stream, qw, kw, vw,
                     ow, qwhT, qwlT, kwhT, kwlT, vwT, owT);
  hipLaunchKernelGGL(k_split, dim3(2048, 2), dim3(256), 0, stream, x, y, Xh,
                     Xl, Yh, Yl, Ym);
  hipLaunchKernelGGL(k_proj, dim3(4, 64, 3), dim3(256), 0, stream, Xh, Xl, Yh,
                     Yl, Ym, qwhT, qwlT, kwhT, kwlT, vwT, qb, kbias, vb, Qh,
                     Ql, Kh, Kl, Vm, Kpart);
  hipLaunchKernelGGL(k_vtr, dim3(8, 64), dim3(256), 0, stream, Vm, Vtr);
  hipLaunchKernelGGL(k_attn, dim3(64, 8), dim3(512), 0, stream, Qh, Ql, Kh,
                     Kl, Vtr, Kpart, Om);
  hipLaunchKernelGGL(k_gemm_out, dim3(4, 64), dim3(256), 0, stream, Om, owT,
                     ob, out);
}

// Round 13
// 116.059 us; speedup vs baseline: 1.1394x; 1.0203x over previous
//
#include <hip/hip_runtime.h>
#include <hip/hip_bf16.h>
#include <hip/hip_fp16.h>

// ---------------------------------------------------------------------------
// Multihead attention with flat-reshape head split + mean-threshold mask.
//   B=8 S=1024 D=512 H=8 -> 64 independent attention problems of (1024 x 64);
//   problem (h,b) = 128 consecutive rows of the 8192x512 projected matrix
//   reinterpreted as 1024x64.
// Precision: Q/K path 3-term bf16 split -> fp32-accurate scores. V/P/O fp16.
// Round-13 (perf only, numerics bit-identical):
//   * k_attn: staging switched from global->reg->ds_write (6 loads + 6
//     ds_writes/thread/chunk) to global_load_lds (3 GLL16/thread/chunk);
//     XOR swizzle moved to the pre-swizzled GLOBAL source (rule #21), LDS
//     image identical. Kills LDS write traffic + frees VGPRs.
//     (Rounds 10-12 lesson: geometry/ILP variants all null at ~47 us; the
//     compiler re-serializes to VGPR 64. Take the mechanical wins.)
//   * k_gemm_out: was 256 blocks = 1 block/CU, 1 wave/SIMD (latency-
//     exposed). Now 128x64 tiles, 512 blocks (2/CU), same dbuf-GLL schedule.
//   * k_wt + k_split merged into k_pre (one dispatch, weight tiles folded
//     into the first 1024 split blocks).
// ---------------------------------------------------------------------------

typedef _Float16 f16;
typedef __attribute__((ext_vector_type(4))) _Float16 f16x4;
typedef __attribute__((ext_vector_type(8))) _Float16 f16x8;
typedef __attribute__((ext_vector_type(8))) short bf16x8;
typedef __attribute__((ext_vector_type(4))) float f32x4;

#define MFMA16(a, b, c) __builtin_amdgcn_mfma_f32_16x16x32_f16((a), (b), (c), 0, 0, 0)
#define MFMAB16(a, b, c) __builtin_amdgcn_mfma_f32_16x16x32_bf16((a), (b), (c), 0, 0, 0)
#define MFMAPV(a, b, c) __builtin_amdgcn_mfma_f32_16x16x16f16((a), (b), (c), 0, 0, 0)

#if defined(__has_builtin) && __has_builtin(__builtin_amdgcn_exp2f)
#define EXPFN(x) __builtin_amdgcn_exp2f(x)
#define QPROJ_SCALE (0.04419417382415922f * 1.4426950408889634f)
#else
#define EXPFN(x) __expf(x)
#define QPROJ_SCALE 0.04419417382415922f
#endif

// async global->LDS, 16B per lane; LDS dst = wave-uniform base + lane*16
#define GLL16(gp, lp)                                       \
  __builtin_amdgcn_global_load_lds(                         \
      (const __attribute__((address_space(1))) void*)(gp),  \
      (__attribute__((address_space(3))) void*)(lp), 16, 0, 0)

__device__ __forceinline__ float b2f(short s) {
  return __uint_as_float(((unsigned)(unsigned short)s) << 16);
}

__device__ __forceinline__ void splitbf(float v, short& h, short& l) {
  unsigned short hu = __bfloat16_as_ushort(__float2bfloat16(v));
  h = (short)hu;
  float hf = __uint_as_float(((unsigned)hu) << 16);
  l = (short)__bfloat16_as_ushort(__float2bfloat16(v - hf));
}

// -------- fused pre-pass: weight transpose+convert AND input split ---------
// grid (2048, 2) x 256 threads. Every block splits its slice of x (y=0) or
// y (y=1). Blocks with bx<512 additionally transpose one 32x32 weight tile
// (wt = y*512+bx in [0,1024): matrix z=wt>>8, tile id wt&255).
__global__ __launch_bounds__(256) void k_pre(
    const float* __restrict__ x, const float* __restrict__ y,
    const float* __restrict__ qw, const float* __restrict__ kw,
    const float* __restrict__ vw, const float* __restrict__ ow,
    short* __restrict__ qh, short* __restrict__ ql, short* __restrict__ kh,
    short* __restrict__ kl, f16* __restrict__ vt, f16* __restrict__ ot,
    short* __restrict__ Xh, short* __restrict__ Xl, short* __restrict__ Yh,
    short* __restrict__ Yl, f16* __restrict__ Ym) {
  const int tid = threadIdx.x;
  const int bx = blockIdx.x;
  const int by = blockIdx.y;
  if (bx < 512) {  // weight-transpose duty
    const int wt = by * 512 + bx;  // 0..1023
    const int z = wt >> 8;
    const int tile = wt & 255;
    const int bxx = tile & 15, byy = tile >> 4;
    const float* W = (z == 0) ? qw : (z == 1) ? kw : (z == 2) ? vw : ow;
    __shared__ float t[32][33];
    const int tx = tid & 31, ty = tid >> 5;
#pragma unroll
    for (int i = 0; i < 32; i += 8)
      t[ty + i][tx] = W[(size_t)(byy * 32 + ty + i) * 512 + bxx * 32 + tx];
    __syncthreads();
#pragma unroll
    for (int i = 0; i < 32; i += 8) {
      size_t idx = (size_t)(bxx * 32 + ty + i) * 512 + byy * 32 + tx;
      float v = t[tx][ty + i];
      if (z < 2) {
        short h, l;
        splitbf(v, h, l);
        if (z == 0) { qh[idx] = h; ql[idx] = l; }
        else { kh[idx] = h; kl[idx] = l; }
      } else {
        if (z == 2) vt[idx] = (f16)v;
        else ot[idx] = (f16)v;
      }
    }
  }
  // split duty (all blocks)
  const float* src = by ? y : x;
  short* dh = by ? Yh : Xh;
  short* dl = by ? Yl : Xl;
  const size_t i = ((size_t)bx * 256 + tid) * 8;
  float4 a = *(const float4*)(src + i);
  float4 b = *(const float4*)(src + i + 4);
  float v[8] = {a.x, a.y, a.z, a.w, b.x, b.y, b.z, b.w};
  bf16x8 h, l;
#pragma unroll
  for (int j = 0; j < 8; ++j) {
    short hh, ll;
    splitbf(v[j], hh, ll);
    h[j] = hh;
    l[j] = ll;
  }
  *(bf16x8*)(dh + i) = h;
  *(bf16x8*)(dl + i) = l;
  if (by) {
    f16x8 m8;
#pragma unroll
    for (int j = 0; j < 8; ++j) m8[j] = (f16)v[j];
    *(f16x8*)(Ym + i) = m8;
  }
}

// ---------- gll-staged, double-buffered f16 GEMM (V-projection) ------------
#define GSTAGE(buf, kk)                                              \
  {                                                                  \
    _Pragma("unroll") for (int j = 0; j < 4; ++j) {                  \
      const int rowu = half + j * 16;                                \
      const int row = rowu + srow;                                   \
      const int slog = sslot ^ ((row >> 1) & 3);                     \
      GLL16(gsb + (size_t)(rb + row) * 512 + (kk) + slog * 8,        \
            &ldsb[buf][rowu][0]);                                    \
    }                                                                \
  }

template <typename OT>
__device__ __forceinline__ void gemm16_gll(const f16* __restrict__ A,
                                           const f16* __restrict__ WT,
                                           const float* __restrict__ bias,
                                           OT* __restrict__ C, int m0, int n0,
                                           f16 (*As)[128][32],
                                           f16 (*Bs)[128][32]) {
  const int tid = threadIdx.x;
  const int wv = tid >> 6, lane = tid & 63;
  const int wm = wv >> 1, wn = wv & 1;
  const int l15 = lane & 15, lg = lane >> 4;
  const int srow = lane >> 2, sslot = lane & 3;

  const f16* gsb = (wv < 2) ? A : WT;
  const int rb = (wv < 2) ? m0 : n0;
  f16(*ldsb)[128][32] = (wv < 2) ? As : Bs;
  const int half = (wv & 1) * 64;

  const f32x4 fz = {0.f, 0.f, 0.f, 0.f};
  f32x4 acc[4][4];
#pragma unroll
  for (int m = 0; m < 4; ++m)
#pragma unroll
    for (int n = 0; n < 4; ++n) acc[m][n] = fz;

  GSTAGE(0, 0);  // prologue
  int cur = 0;
  for (int k0 = 0; k0 < 512; k0 += 32) {
    __syncthreads();  // drains prefetch -> buf[cur] ready; prev reads done
    if (k0 < 480) GSTAGE(cur ^ 1, k0 + 32);  // in flight under compute
    f16x8 af[4], bf[4];
#pragma unroll
    for (int m = 0; m < 4; ++m) {
      const int r = wm * 64 + m * 16 + l15;
      af[m] = *(const f16x8*)&As[cur][r][(lg ^ ((r >> 1) & 3)) * 8];
    }
#pragma unroll
    for (int n = 0; n < 4; ++n) {
      const int r = wn * 64 + n * 16 + l15;
      bf[n] = *(const f16x8*)&Bs[cur][r][(lg ^ ((r >> 1) & 3)) * 8];
    }
#pragma unroll
    for (int m = 0; m < 4; ++m)
#pragma unroll
      for (int n = 0; n < 4; ++n) acc[m][n] = MFMA16(af[m], bf[n], acc[m][n]);
    cur ^= 1;
  }
#pragma unroll
  for (int n = 0; n < 4; ++n) {
    const int col = n0 + wn * 64 + n * 16 + l15;
    const float b = bias[col];
#pragma unroll
    for (int m = 0; m < 4; ++m) {
      const int row = m0 + wm * 64 + m * 16 + lg * 4;
#pragma unroll
      for (int r = 0; r < 4; ++r)
        C[(size_t)(row + r) * 512 + col] = (OT)(acc[m][n][r] + b);
    }
  }
}

// ------------- output GEMM: 128x64 tiles, 512 blocks (2/CU) ----------------
#define OSTAGE(buf, kk)                                                       \
  {                                                                           \
    if (wv < 2) {                                                             \
      _Pragma("unroll") for (int j = 0; j < 4; ++j) {                         \
        const int rowu = wv * 64 + j * 16;                                    \
        const int row = rowu + srow;                                          \
        const int slog = sslot ^ ((row >> 1) & 3);                            \
        GLL16(Om + (size_t)(m0 + row) * 512 + (kk) + slog * 8,                \
              &As[buf][rowu][0]);                                             \
      }                                                                       \
    } else {                                                                  \
      _Pragma("unroll") for (int j = 0; j < 2; ++j) {                         \
        const int rowu = (wv - 2) * 32 + j * 16;                              \
        const int row = rowu + srow;                                          \
        const int slog = sslot ^ ((row >> 1) & 3);                            \
        GLL16(owT + (size_t)(n0 + row) * 512 + (kk) + slog * 8,               \
              &Bs[buf][rowu][0]);                                             \
      }                                                                       \
    }                                                                         \
  }

__global__ __launch_bounds__(256) void k_gemm_out(const f16* __restrict__ Om,
                                                  const f16* __restrict__ owT,
                                                  const float* __restrict__ ob,
                                                  float* __restrict__ out) {
  __shared__ __align__(16) f16 As[2][128][32];  // 16 KB
  __shared__ __align__(16) f16 Bs[2][64][32];   // 8 KB
  // grid (8, 64) = 512 blocks; XCD-bijective swizzle (512 = 8 x 64)
  const int lid = blockIdx.x + (blockIdx.y << 3);
  const int swz = ((lid & 7) << 6) + (lid >> 3);
  const int m0 = (swz >> 3) * 128, n0 = (swz & 7) * 64;
  const int tid = threadIdx.x;
  const int wv = tid >> 6, lane = tid & 63;
  const int wm = wv >> 1, wn = wv & 1;  // wave tile 64(m) x 32(n)
  const int l15 = lane & 15, lg = lane >> 4;
  const int srow = lane >> 2, sslot = lane & 3;

  const f32x4 fz = {0.f, 0.f, 0.f, 0.f};
  f32x4 acc[4][2];
#pragma unroll
  for (int m = 0; m < 4; ++m)
#pragma unroll
    for (int n = 0; n < 2; ++n) acc[m][n] = fz;

  OSTAGE(0, 0);
  int cur = 0;
  for (int k0 = 0; k0 < 512; k0 += 32) {
    __syncthreads();
    if (k0 < 480) OSTAGE(cur ^ 1, k0 + 32);
    f16x8 af[4], bf[2];
#pragma unroll
    for (int m = 0; m < 4; ++m) {
      const int r = wm * 64 + m * 16 + l15;
      af[m] = *(const f16x8*)&As[cur][r][(lg ^ ((r >> 1) & 3)) * 8];
    }
#pragma unroll
    for (int n = 0; n < 2; ++n) {
      const int r = wn * 32 + n * 16 + l15;
      bf[n] = *(const f16x8*)&Bs[cur][r][(lg ^ ((r >> 1) & 3)) * 8];
    }
#pragma unroll
    for (int m = 0; m < 4; ++m)
#pragma unroll
      for (int n = 0; n < 2; ++n) acc[m][n] = MFMA16(af[m], bf[n], acc[m][n]);
    cur ^= 1;
  }
#pragma unroll
  for (int n = 0; n < 2; ++n) {
    const int col = n0 + wn * 32 + n * 16 + l15;
    const float b = ob[col];
#pragma unroll
    for (int m = 0; m < 4; ++m) {
      const int row = m0 + wm * 64 + m * 16 + lg * 4;
#pragma unroll
      for (int r = 0; r < 4; ++r)
        out[(size_t)(row + r) * 512 + col] = acc[m][n][r] + b;
    }
  }
}

// ---------------- merged projections: Q,K (split) + V (f16) ----------------
#define PSTAGE(buf, kk)                                             \
  {                                                                 \
    _Pragma("unroll") for (int j = 0; j < 8; ++j) {                 \
      const int row = j * 16 + srow;                                \
      const int slog = sslot ^ ((row >> 1) & 3);                    \
      GLL16(gsb + (size_t)(rb + row) * 512 + (kk) + slog * 8,       \
            &sm4[buf][wv][j * 16][0]);                              \
    }                                                               \
  }

__global__ __launch_bounds__(256) void k_proj(
    const short* __restrict__ Xh, const short* __restrict__ Xl,
    const short* __restrict__ Yh, const short* __restrict__ Yl,
    const f16* __restrict__ Ym, const short* __restrict__ qwh,
    const short* __restrict__ qwl, const short* __restrict__ kwh,
    const short* __restrict__ kwl, const f16* __restrict__ vwT,
    const float* __restrict__ qb, const float* __restrict__ kbias,
    const float* __restrict__ vb, short* __restrict__ Qh,
    short* __restrict__ Ql, short* __restrict__ Kh, short* __restrict__ Kl,
    f16* __restrict__ Vm, float* __restrict__ Kpart) {
  __shared__ __align__(16) short sm4[2][4][128][32];  // 64 KB (double-buffer)
  const int lid = blockIdx.x + (blockIdx.y << 2);
  const int swz = ((lid & 7) << 5) + (lid >> 3);  // XCD-bijective (256=8x32)
  const int nt = swz & 3, mt = swz >> 2;
  const int m0 = mt * 128, n0 = nt * 128;
  const int z = blockIdx.z;
  if (z == 2) {
    gemm16_gll<f16>(Ym, vwT, vb, Vm, m0, n0, (f16(*)[128][32]) & sm4[0][0][0][0],
                    (f16(*)[128][32]) & sm4[0][2][0][0]);
    return;
  }
  const short* Agh = z ? Yh : Xh;
  const short* Agl = z ? Yl : Xl;
  const short* Wh = z ? kwh : qwh;
  const short* Wl = z ? kwl : qwl;
  const float* bias = z ? kbias : qb;
  short* Ch = z ? Kh : Qh;
  short* Cl = z ? Kl : Ql;
  const float osc = z ? 1.f : (float)QPROJ_SCALE;  // Q pre-scaled for attn

  const int tid = threadIdx.x;
  const int wv = tid >> 6, lane = tid & 63;
  const int wm = wv >> 1, wn = wv & 1;
  const int l15 = lane & 15, lg = lane >> 4;
  const int srow = lane >> 2, sslot = lane & 3;

  // wave wv stages stream wv: 0=A-hi, 1=A-lo, 2=B-hi, 3=B-lo (8 KB each)
  const short* gsb = (wv == 0) ? Agh : (wv == 1) ? Agl : (wv == 2) ? Wh : Wl;
  const int rb = (wv < 2) ? m0 : n0;

  const f32x4 fz = {0.f, 0.f, 0.f, 0.f};
  f32x4 acc[4][4];
#pragma unroll
  for (int m = 0; m < 4; ++m)
#pragma unroll
    for (int n = 0; n < 4; ++n) acc[m][n] = fz;

  PSTAGE(0, 0);  // prologue
  int cur = 0;
  for (int k0 = 0; k0 < 512; k0 += 32) {
    __syncthreads();  // drains prefetch -> buf[cur] ready; prev reads done
    if (k0 < 480) PSTAGE(cur ^ 1, k0 + 32);  // in flight under compute
    bf16x8 afh[4], afl[4], bfh[4], bfl[4];
#pragma unroll
    for (int m = 0; m < 4; ++m) {
      const int r = wm * 64 + m * 16 + l15;
      const int sl = (lg ^ ((r >> 1) & 3)) * 8;
      afh[m] = *(const bf16x8*)&sm4[cur][0][r][sl];
      afl[m] = *(const bf16x8*)&sm4[cur][1][r][sl];
    }
#pragma unroll
    for (int n = 0; n < 4; ++n) {
      const int r = wn * 64 + n * 16 + l15;
      const int sl = (lg ^ ((r >> 1) & 3)) * 8;
      bfh[n] = *(const bf16x8*)&sm4[cur][2][r][sl];
      bfl[n] = *(const bf16x8*)&sm4[cur][3][r][sl];
    }
#pragma unroll
    for (int m = 0; m < 4; ++m)
#pragma unroll
      for (int n = 0; n < 4; ++n) {
        acc[m][n] = MFMAB16(afh[m], bfh[n], acc[m][n]);
        acc[m][n] = MFMAB16(afh[m], bfl[n], acc[m][n]);
        acc[m][n] = MFMAB16(afl[m], bfh[n], acc[m][n]);
      }
    cur ^= 1;
  }
  // epilogue: split-bf16 output (+ deterministic K column partial sums)
  float csum[4];
#pragma unroll
  for (int n = 0; n < 4; ++n) {
    const int col = n0 + wn * 64 + n * 16 + l15;
    const float b = bias[col];
    csum[n] = 16.f * b;
#pragma unroll
    for (int m = 0; m < 4; ++m) {
      const int row = m0 + wm * 64 + m * 16 + lg * 4;
#pragma unroll
      for (int r = 0; r < 4; ++r) {
        const float vraw = acc[m][n][r] + b;
        csum[n] += acc[m][n][r];
        short h, l;
        splitbf(vraw * osc, h, l);
        const size_t idx = (size_t)(row + r) * 512 + col;
        Ch[idx] = h;
        Cl[idx] = l;
      }
    }
  }
  if (z == 1) {
    // block-local column reduction (deterministic): 128 cols x 8 contributors
    float* cred = (float*)&sm4[0][0][0][0];
    __syncthreads();  // all waves done with LDS tiles
#pragma unroll
    for (int n = 0; n < 4; ++n)
      cred[(wn * 64 + n * 16 + l15) * 8 + wm * 4 + lg] = csum[n];
    __syncthreads();
    if (tid < 64) {
      float s = 0.f;
#pragma unroll
      for (int j = 0; j < 8; ++j)
        s += cred[tid * 8 + j] + cred[(tid + 64) * 8 + j];
      Kpart[((size_t)mt * 4 + nt) * 64 + tid] = s;  // mt == problem p
    }
  }
}

// ----------------------- V transpose (per problem) -------------------------
// Vm [8192][512] f16 -> Vt [64 p][64 dh][1024 k] f16.
__global__ __launch_bounds__(256) void k_vtr(const f16* __restrict__ Vm,
                                             f16* __restrict__ Vt) {
  const int p = blockIdx.y;
  const int j0 = blockIdx.x * 16;
  __shared__ f16 L[16][520];
  const int tid = threadIdx.x;
#pragma unroll
  for (int it = 0; it < 4; ++it) {
    int idx = it * 256 + tid;
    int row = idx >> 6, oct = idx & 63;
    *(f16x8*)&L[row][oct * 8] =
        *(const f16x8*)&Vm[(size_t)(p * 128 + j0 + row) * 512 + oct * 8];
  }
  __syncthreads();
#pragma unroll
  for (int it = 0; it < 4; ++it) {
    int idx = it * 256 + tid;
    int dh = idx >> 4, j = idx & 15;
    f16x8 v;
#pragma unroll
    for (int g = 0; g < 8; ++g) v[g] = L[j][g * 64 + dh];
    *(f16x8*)&Vt[((size_t)p * 64 + dh) * 1024 + (j0 + j) * 8] = v;
  }
}

// ------------------------------- attention ---------------------------------
// grid (64 problems, 8 q-tiles), 512 threads = 8 waves, ONE 16-q group/wave.
// 64-key chunks, double-buffered LDS (48 KB), one barrier per chunk.
// Staging via global_load_lds (3 GLL16/thread/chunk): LDS dest is linear
// (wave base + lane*16); XOR swizzle applied to the GLOBAL source (rule #21)
// -> LDS image identical to rounds 9-12, reads unchanged.
#define STAGE(b, cc)                                       \
  {                                                        \
    GLL16(KhSrc + (cc) * 4096, &KhS[b][skey][slot8 * 8]);  \
    GLL16(KlSrc + (cc) * 4096, &KlS[b][skey][slot8 * 8]);  \
    GLL16(VSrc + (cc) * 64, &Vs[b][skey][slot8 * 8]);      \
  }

// one 64-key chunk with compile-time buffer index cb_
#define CHUNK(cb_, c_)                                                        \
  {                                                                           \
    __syncthreads(); /* drains STAGE of buf[cb_]; prev buf reads done */      \
    if ((c_) < 15) STAGE((cb_) ^ 1, (c_) + 1); /* async under compute */      \
    __builtin_amdgcn_s_setprio(1);                                            \
    f32x4 aa[4];                                                              \
    _Pragma("unroll") for (int t = 0; t < 4; ++t) {                           \
      const int krow = t * 16 + l15;                                          \
      const int ksw = l15 & 7; /* krow&7 == l15&7 */                          \
      bf16x8 kh0 = *(const bf16x8*)&KhS[cb_][krow][(lg ^ ksw) * 8];           \
      bf16x8 kh1 = *(const bf16x8*)&KhS[cb_][krow][((4 + lg) ^ ksw) * 8];     \
      bf16x8 kl0 = *(const bf16x8*)&KlS[cb_][krow][(lg ^ ksw) * 8];           \
      bf16x8 kl1 = *(const bf16x8*)&KlS[cb_][krow][((4 + lg) ^ ksw) * 8];     \
      f32x4 s1 = fz, s2 = fz;                                                 \
      s1 = MFMAB16(kh0, qh0, s1);                                             \
      s2 = MFMAB16(kh1, qh1, s2);                                             \
      s1 = MFMAB16(kl0, qh0, s1);                                             \
      s2 = MFMAB16(kl1, qh1, s2);                                             \
      s1 = MFMAB16(kh0, ql0, s1);                                             \
      s2 = MFMAB16(kh1, ql1, s2);                                             \
      aa[t] = s1 + s2;                                                        \
    }                                                                         \
    f16x4 va[4][4];                                                           \
    _Pragma("unroll") for (int d0 = 0; d0 < 4; ++d0) {                        \
      const int vrow = d0 * 16 + l15;                                         \
      const int vsw = l15 & 7;                                                \
      _Pragma("unroll") for (int t = 0; t < 4; ++t)                           \
        va[d0][t] = *(const f16x4*)&Vs[cb_][vrow]                             \
                        [(((t * 2 + (lg >> 1)) ^ vsw) * 8) + (lg & 1) * 4];   \
    }                                                                         \
    f16x4 pf[4];                                                              \
    _Pragma("unroll") for (int t = 0; t < 4; ++t)                             \
      _Pragma("unroll") for (int r = 0; r < 4; ++r) {                         \
        float v = aa[t][r];                                                   \
        pf[t][r] = (f16)((v > sm) ? EXPFN(v) : 0.f);                          \
      }                                                                       \
    _Pragma("unroll") for (int t = 0; t < 4; ++t) {                           \
      od = MFMAPV(kones, pf[t], od);                                          \
      _Pragma("unroll") for (int d0 = 0; d0 < 4; ++d0)                        \
        oac[d0] = MFMAPV(va[d0][t], pf[t], oac[d0]);                          \
    }                                                                         \
    __builtin_amdgcn_s_setprio(0);                                            \
  }

__global__ __launch_bounds__(512, 4) void k_attn(
    const short* __restrict__ Qh, const short* __restrict__ Ql,
    const short* __restrict__ Kh, const short* __restrict__ Kl,
    const f16* __restrict__ Vt, const float* __restrict__ Kpart,
    f16* __restrict__ Om) {
  constexpr int S = 1024, DH = 64;
  const int p = blockIdx.x;
  const int qt = blockIdx.y;
  const size_t pb = (size_t)p * S * DH;
  const short* Qhp = Qh + pb;
  const short* Qlp = Ql + pb;
  const short* Khp = Kh + pb;
  const short* Klp = Kl + pb;
  const f16* Vtp = Vt + pb;  // [64 dh][1024 k]
  f16* Op = Om + pb;

  const int tid = threadIdx.x;
  const int w = tid >> 6, lane = tid & 63;
  const int l15 = lane & 15, lg = lane >> 4;

  __shared__ __align__(16) short KhS[2][64][64];
  __shared__ __align__(16) short KlS[2][64][64];
  __shared__ __align__(16) f16 Vs[2][64][64];  // 48 KB total

  // GLL staging: thread -> (row skey, 16B slot slot8); source pre-swizzled.
  // LDS dest offset = skey*128 + slot8*16 = wave_base + lane*16  (uniform).
  const int skey = tid >> 3;
  const int slot8 = tid & 7;
  const int ssw = skey & 7;
  const short* KhSrc = Khp + skey * 64 + (slot8 ^ ssw) * 8;
  const short* KlSrc = Klp + skey * 64 + (slot8 ^ ssw) * 8;
  const f16* VSrc = Vtp + (size_t)skey * 1024 + (slot8 ^ ssw) * 8;

  STAGE(0, 0);  // async; drained by the first barrier

  // this wave's 16-q group (Q pre-scaled by QPROJ_SCALE)
  const int qrow = qt * 128 + w * 16;
  const size_t qo = (size_t)(qrow + l15) * DH + lg * 8;
  bf16x8 qh0 = *(const bf16x8*)(Qhp + qo);
  bf16x8 ql0 = *(const bf16x8*)(Qlp + qo);
  bf16x8 qh1 = *(const bf16x8*)(Qhp + qo + 32);
  bf16x8 ql1 = *(const bf16x8*)(Qlp + qo + 32);

  // threshold: mean_q = (Qscaled_q . Ksum) / 1024, Ksum = sum of 4 partials
  const float* kp = Kpart + (size_t)p * 256;
  float km0[8], km1[8];
#pragma unroll
  for (int j = 0; j < 8; ++j) { km0[j] = 0.f; km1[j] = 0.f; }
#pragma unroll
  for (int pt = 0; pt < 4; ++pt) {
    const float* bb = kp + pt * 64;
#pragma unroll
    for (int j = 0; j < 8; ++j) {
      km0[j] += bb[lg * 8 + j];
      km1[j] += bb[32 + lg * 8 + j];
    }
  }
  float sm = 0.f;
#pragma unroll
  for (int j = 0; j < 8; ++j) {
    sm += (b2f(qh0[j]) + b2f(ql0[j])) * km0[j] +
          (b2f(qh1[j]) + b2f(ql1[j])) * km1[j];
  }
  sm += __shfl_xor(sm, 16);
  sm += __shfl_xor(sm, 32);
  sm *= (1.f / 1024.f);

  const f32x4 fz = {0.f, 0.f, 0.f, 0.f};
  const f16x4 kones = {(f16)1.f, (f16)1.f, (f16)1.f, (f16)1.f};
  f32x4 oac[4];
#pragma unroll
  for (int d = 0; d < 4; ++d) oac[d] = fz;
  f32x4 od = fz;

  for (int cc = 0; cc < 16; cc += 2) {
    CHUNK(0, cc);
    CHUNK(1, cc + 1);
  }

  const float inv = 1.f / od[0];  // all 4 regs equal (sum over all k)
#pragma unroll
  for (int d0 = 0; d0 < 4; ++d0) {
    f16x4 o0;
#pragma unroll
    for (int r = 0; r < 4; ++r) o0[r] = (f16)(oac[d0][r] * inv);
    *(f16x4*)&Op[(size_t)(qrow + l15) * DH + d0 * 16 + lg * 4] = o0;
  }
}

// ------------------------------- launcher ----------------------------------
extern "C" void kernel_launch(void* const* d_in, const int* in_sizes, int n_in,
                              void* d_out, int out_size, void* d_ws,
                              size_t ws_size, hipStream_t stream) {
  const float* x = (const float*)d_in[0];
  const float* y = (const float*)d_in[1];
  const float* qw = (const float*)d_in[2];
  const float* qb = (const float*)d_in[3];
  const float* kw = (const float*)d_in[4];
  const float* kbias = (const float*)d_in[5];
  const float* vw = (const float*)d_in[6];
  const float* vb = (const float*)d_in[7];
  const float* ow = (const float*)d_in[8];
  const float* ob = (const float*)d_in[9];
  float* out = (float*)d_out;

  char* ws = (char*)d_ws;
  const size_t WT_B = 512ull * 512 * 2;    // 512 KB
  const size_t MAT_B = 8192ull * 512 * 2;  // 8 MB
  short* qwhT = (short*)(ws + 0 * WT_B);
  short* qwlT = (short*)(ws + 1 * WT_B);
  short* kwhT = (short*)(ws + 2 * WT_B);
  short* kwlT = (short*)(ws + 3 * WT_B);
  f16* vwT = (f16*)(ws + 4 * WT_B);
  f16* owT = (f16*)(ws + 5 * WT_B);
  char* m = ws + 6 * WT_B;
  short* Qh = (short*)(m + 0 * MAT_B);
  short* Ql = (short*)(m + 1 * MAT_B);
  short* Kh = (short*)(m + 2 * MAT_B);
  short* Kl = (short*)(m + 3 * MAT_B);
  f16* Vm = (f16*)(m + 4 * MAT_B);
  short* Xh = (short*)(m + 5 * MAT_B);
  short* Xl = (short*)(m + 6 * MAT_B);
  short* Yh = (short*)(m + 7 * MAT_B);
  short* Yl = (short*)(m + 8 * MAT_B);
  f16* Ym = (f16*)(m + 9 * MAT_B);
  float* Kpart = (float*)(m + 10 * MAT_B);  // 64 KB; total ~83.1 MB
  // dead-buffer aliases (stream order makes these safe):
  f16* Vtr = (f16*)Xh;  // k_vtr runs after k_proj (Xh consumed)
  f16* Om = (f16*)Yh;   // k_attn runs after k_proj (Yh consumed)

  hipLaunchKernelGGL(k_pre, dim3(2048, 2), dim3(256), 0, stream, x, y, qw, kw,
                     vw, ow, qwhT, qwlT, kwhT, kwlT, vwT, owT, Xh, Xl, Yh, Yl,
                     Ym);
  hipLaunchKernelGGL(k_proj, dim3(4, 64, 3), dim3(256), 0, stream, Xh, Xl, Yh,
                     Yl, Ym, qwhT, qwlT, kwhT, kwlT, vwT, qb, kbias, vb, Qh,
                     Ql, Kh, Kl, Vm, Kpart);
  hipLaunchKernelGGL(k_vtr, dim3(8, 64), dim3(256), 0, stream, Vm, Vtr);
  hipLaunchKernelGGL(k_attn, dim3(64, 8), dim3(512), 0, stream, Qh, Ql, Kh,
                     Kl, Vtr, Kpart, Om);
  hipLaunchKernelGGL(k_gemm_out, dim3(8, 64), dim3(256), 0, stream, Om, owT,
                     ob, out);
}

// Round 14
// 115.341 us; speedup vs baseline: 1.1465x; 1.0062x over previous
//
#include <hip/hip_runtime.h>
#include <hip/hip_bf16.h>
#include <hip/hip_fp16.h>

// ---------------------------------------------------------------------------
// Multihead attention with flat-reshape head split + mean-threshold mask.
//   B=8 S=1024 D=512 H=8 -> 64 independent attention problems of (1024 x 64);
//   problem (h,b) = 128 consecutive rows of the 8192x512 projected matrix
//   reinterpreted as 1024x64.
// Precision: Q/K path 3-term bf16 split -> fp32-accurate scores. V/P/O fp16.
// Round-14 (k_attn only): key-split wave pairs.
//   Pipe audit of round 13: MFMA-busy 18.6 us (= algorithm floor), VALU 16.3,
//   LDS-read pipe ~30.7 us (66% -- most loaded, never counted before).
//   Round 10 halved LDS but also TLP (null); round 11 had both but broken
//   swizzle (regression). This round: round-9 TLP + round-10 LDS/wave:
//   8 waves x 32 q (2 groups) x HALF keys (2 t-tiles); K/V fragment reads
//   per wave per chunk halve (8 b128 + 8 b64); per-wave MFMA unchanged.
//   Wave pairs (w, w+4) merge partial O/den via reused staging LDS.
// ---------------------------------------------------------------------------

typedef _Float16 f16;
typedef __attribute__((ext_vector_type(4))) _Float16 f16x4;
typedef __attribute__((ext_vector_type(8))) _Float16 f16x8;
typedef __attribute__((ext_vector_type(8))) short bf16x8;
typedef __attribute__((ext_vector_type(4))) float f32x4;

#define MFMA16(a, b, c) __builtin_amdgcn_mfma_f32_16x16x32_f16((a), (b), (c), 0, 0, 0)
#define MFMAB16(a, b, c) __builtin_amdgcn_mfma_f32_16x16x32_bf16((a), (b), (c), 0, 0, 0)
#define MFMAPV(a, b, c) __builtin_amdgcn_mfma_f32_16x16x16f16((a), (b), (c), 0, 0, 0)

#if defined(__has_builtin) && __has_builtin(__builtin_amdgcn_exp2f)
#define EXPFN(x) __builtin_amdgcn_exp2f(x)
#define QPROJ_SCALE (0.04419417382415922f * 1.4426950408889634f)
#else
#define EXPFN(x) __expf(x)
#define QPROJ_SCALE 0.04419417382415922f
#endif

// async global->LDS, 16B per lane; LDS dst = wave-uniform base + lane*16
#define GLL16(gp, lp)                                       \
  __builtin_amdgcn_global_load_lds(                         \
      (const __attribute__((address_space(1))) void*)(gp),  \
      (__attribute__((address_space(3))) void*)(lp), 16, 0, 0)

__device__ __forceinline__ float b2f(short s) {
  return __uint_as_float(((unsigned)(unsigned short)s) << 16);
}

__device__ __forceinline__ void splitbf(float v, short& h, short& l) {
  unsigned short hu = __bfloat16_as_ushort(__float2bfloat16(v));
  h = (short)hu;
  float hf = __uint_as_float(((unsigned)hu) << 16);
  l = (short)__bfloat16_as_ushort(__float2bfloat16(v - hf));
}

// -------- fused pre-pass: weight transpose+convert AND input split ---------
__global__ __launch_bounds__(256) void k_pre(
    const float* __restrict__ x, const float* __restrict__ y,
    const float* __restrict__ qw, const float* __restrict__ kw,
    const float* __restrict__ vw, const float* __restrict__ ow,
    short* __restrict__ qh, short* __restrict__ ql, short* __restrict__ kh,
    short* __restrict__ kl, f16* __restrict__ vt, f16* __restrict__ ot,
    short* __restrict__ Xh, short* __restrict__ Xl, short* __restrict__ Yh,
    short* __restrict__ Yl, f16* __restrict__ Ym) {
  const int tid = threadIdx.x;
  const int bx = blockIdx.x;
  const int by = blockIdx.y;
  if (bx < 512) {  // weight-transpose duty
    const int wt = by * 512 + bx;  // 0..1023
    const int z = wt >> 8;
    const int tile = wt & 255;
    const int bxx = tile & 15, byy = tile >> 4;
    const float* W = (z == 0) ? qw : (z == 1) ? kw : (z == 2) ? vw : ow;
    __shared__ float t[32][33];
    const int tx = tid & 31, ty = tid >> 5;
#pragma unroll
    for (int i = 0; i < 32; i += 8)
      t[ty + i][tx] = W[(size_t)(byy * 32 + ty + i) * 512 + bxx * 32 + tx];
    __syncthreads();
#pragma unroll
    for (int i = 0; i < 32; i += 8) {
      size_t idx = (size_t)(bxx * 32 + ty + i) * 512 + byy * 32 + tx;
      float v = t[tx][ty + i];
      if (z < 2) {
        short h, l;
        splitbf(v, h, l);
        if (z == 0) { qh[idx] = h; ql[idx] = l; }
        else { kh[idx] = h; kl[idx] = l; }
      } else {
        if (z == 2) vt[idx] = (f16)v;
        else ot[idx] = (f16)v;
      }
    }
  }
  // split duty (all blocks)
  const float* src = by ? y : x;
  short* dh = by ? Yh : Xh;
  short* dl = by ? Yl : Xl;
  const size_t i = ((size_t)bx * 256 + tid) * 8;
  float4 a = *(const float4*)(src + i);
  float4 b = *(const float4*)(src + i + 4);
  float v[8] = {a.x, a.y, a.z, a.w, b.x, b.y, b.z, b.w};
  bf16x8 h, l;
#pragma unroll
  for (int j = 0; j < 8; ++j) {
    short hh, ll;
    splitbf(v[j], hh, ll);
    h[j] = hh;
    l[j] = ll;
  }
  *(bf16x8*)(dh + i) = h;
  *(bf16x8*)(dl + i) = l;
  if (by) {
    f16x8 m8;
#pragma unroll
    for (int j = 0; j < 8; ++j) m8[j] = (f16)v[j];
    *(f16x8*)(Ym + i) = m8;
  }
}

// ---------- gll-staged, double-buffered f16 GEMM (V-projection) ------------
#define GSTAGE(buf, kk)                                              \
  {                                                                  \
    _Pragma("unroll") for (int j = 0; j < 4; ++j) {                  \
      const int rowu = half + j * 16;                                \
      const int row = rowu + srow;                                   \
      const int slog = sslot ^ ((row >> 1) & 3);                     \
      GLL16(gsb + (size_t)(rb + row) * 512 + (kk) + slog * 8,        \
            &ldsb[buf][rowu][0]);                                    \
    }                                                                \
  }

template <typename OT>
__device__ __forceinline__ void gemm16_gll(const f16* __restrict__ A,
                                           const f16* __restrict__ WT,
                                           const float* __restrict__ bias,
                                           OT* __restrict__ C, int m0, int n0,
                                           f16 (*As)[128][32],
                                           f16 (*Bs)[128][32]) {
  const int tid = threadIdx.x;
  const int wv = tid >> 6, lane = tid & 63;
  const int wm = wv >> 1, wn = wv & 1;
  const int l15 = lane & 15, lg = lane >> 4;
  const int srow = lane >> 2, sslot = lane & 3;

  const f16* gsb = (wv < 2) ? A : WT;
  const int rb = (wv < 2) ? m0 : n0;
  f16(*ldsb)[128][32] = (wv < 2) ? As : Bs;
  const int half = (wv & 1) * 64;

  const f32x4 fz = {0.f, 0.f, 0.f, 0.f};
  f32x4 acc[4][4];
#pragma unroll
  for (int m = 0; m < 4; ++m)
#pragma unroll
    for (int n = 0; n < 4; ++n) acc[m][n] = fz;

  GSTAGE(0, 0);  // prologue
  int cur = 0;
  for (int k0 = 0; k0 < 512; k0 += 32) {
    __syncthreads();  // drains prefetch -> buf[cur] ready; prev reads done
    if (k0 < 480) GSTAGE(cur ^ 1, k0 + 32);  // in flight under compute
    f16x8 af[4], bf[4];
#pragma unroll
    for (int m = 0; m < 4; ++m) {
      const int r = wm * 64 + m * 16 + l15;
      af[m] = *(const f16x8*)&As[cur][r][(lg ^ ((r >> 1) & 3)) * 8];
    }
#pragma unroll
    for (int n = 0; n < 4; ++n) {
      const int r = wn * 64 + n * 16 + l15;
      bf[n] = *(const f16x8*)&Bs[cur][r][(lg ^ ((r >> 1) & 3)) * 8];
    }
#pragma unroll
    for (int m = 0; m < 4; ++m)
#pragma unroll
      for (int n = 0; n < 4; ++n) acc[m][n] = MFMA16(af[m], bf[n], acc[m][n]);
    cur ^= 1;
  }
#pragma unroll
  for (int n = 0; n < 4; ++n) {
    const int col = n0 + wn * 64 + n * 16 + l15;
    const float b = bias[col];
#pragma unroll
    for (int m = 0; m < 4; ++m) {
      const int row = m0 + wm * 64 + m * 16 + lg * 4;
#pragma unroll
      for (int r = 0; r < 4; ++r)
        C[(size_t)(row + r) * 512 + col] = (OT)(acc[m][n][r] + b);
    }
  }
}

// ------------- output GEMM: 128x64 tiles, 512 blocks (2/CU) ----------------
#define OSTAGE(buf, kk)                                                       \
  {                                                                           \
    if (wv < 2) {                                                             \
      _Pragma("unroll") for (int j = 0; j < 4; ++j) {                         \
        const int rowu = wv * 64 + j * 16;                                    \
        const int row = rowu + srow;                                          \
        const int slog = sslot ^ ((row >> 1) & 3);                            \
        GLL16(Om + (size_t)(m0 + row) * 512 + (kk) + slog * 8,                \
              &As[buf][rowu][0]);                                             \
      }                                                                       \
    } else {                                                                  \
      _Pragma("unroll") for (int j = 0; j < 2; ++j) {                         \
        const int rowu = (wv - 2) * 32 + j * 16;                              \
        const int row = rowu + srow;                                          \
        const int slog = sslot ^ ((row >> 1) & 3);                            \
        GLL16(owT + (size_t)(n0 + row) * 512 + (kk) + slog * 8,               \
              &Bs[buf][rowu][0]);                                             \
      }                                                                       \
    }                                                                         \
  }

__global__ __launch_bounds__(256) void k_gemm_out(const f16* __restrict__ Om,
                                                  const f16* __restrict__ owT,
                                                  const float* __restrict__ ob,
                                                  float* __restrict__ out) {
  __shared__ __align__(16) f16 As[2][128][32];  // 16 KB
  __shared__ __align__(16) f16 Bs[2][64][32];   // 8 KB
  // grid (8, 64) = 512 blocks; XCD-bijective swizzle (512 = 8 x 64)
  const int lid = blockIdx.x + (blockIdx.y << 3);
  const int swz = ((lid & 7) << 6) + (lid >> 3);
  const int m0 = (swz >> 3) * 128, n0 = (swz & 7) * 64;
  const int tid = threadIdx.x;
  const int wv = tid >> 6, lane = tid & 63;
  const int wm = wv >> 1, wn = wv & 1;  // wave tile 64(m) x 32(n)
  const int l15 = lane & 15, lg = lane >> 4;
  const int srow = lane >> 2, sslot = lane & 3;

  const f32x4 fz = {0.f, 0.f, 0.f, 0.f};
  f32x4 acc[4][2];
#pragma unroll
  for (int m = 0; m < 4; ++m)
#pragma unroll
    for (int n = 0; n < 2; ++n) acc[m][n] = fz;

  OSTAGE(0, 0);
  int cur = 0;
  for (int k0 = 0; k0 < 512; k0 += 32) {
    __syncthreads();
    if (k0 < 480) OSTAGE(cur ^ 1, k0 + 32);
    f16x8 af[4], bf[2];
#pragma unroll
    for (int m = 0; m < 4; ++m) {
      const int r = wm * 64 + m * 16 + l15;
      af[m] = *(const f16x8*)&As[cur][r][(lg ^ ((r >> 1) & 3)) * 8];
    }
#pragma unroll
    for (int n = 0; n < 2; ++n) {
      const int r = wn * 32 + n * 16 + l15;
      bf[n] = *(const f16x8*)&Bs[cur][r][(lg ^ ((r >> 1) & 3)) * 8];
    }
#pragma unroll
    for (int m = 0; m < 4; ++m)
#pragma unroll
      for (int n = 0; n < 2; ++n) acc[m][n] = MFMA16(af[m], bf[n], acc[m][n]);
    cur ^= 1;
  }
#pragma unroll
  for (int n = 0; n < 2; ++n) {
    const int col = n0 + wn * 32 + n * 16 + l15;
    const float b = ob[col];
#pragma unroll
    for (int m = 0; m < 4; ++m) {
      const int row = m0 + wm * 64 + m * 16 + lg * 4;
#pragma unroll
      for (int r = 0; r < 4; ++r)
        out[(size_t)(row + r) * 512 + col] = acc[m][n][r] + b;
    }
  }
}

// ---------------- merged projections: Q,K (split) + V (f16) ----------------
#define PSTAGE(buf, kk)                                             \
  {                                                                 \
    _Pragma("unroll") for (int j = 0; j < 8; ++j) {                 \
      const int row = j * 16 + srow;                                \
      const int slog = sslot ^ ((row >> 1) & 3);                    \
      GLL16(gsb + (size_t)(rb + row) * 512 + (kk) + slog * 8,       \
            &sm4[buf][wv][j * 16][0]);                              \
    }                                                               \
  }

__global__ __launch_bounds__(256) void k_proj(
    const short* __restrict__ Xh, const short* __restrict__ Xl,
    const short* __restrict__ Yh, const short* __restrict__ Yl,
    const f16* __restrict__ Ym, const short* __restrict__ qwh,
    const short* __restrict__ qwl, const short* __restrict__ kwh,
    const short* __restrict__ kwl, const f16* __restrict__ vwT,
    const float* __restrict__ qb, const float* __restrict__ kbias,
    const float* __restrict__ vb, short* __restrict__ Qh,
    short* __restrict__ Ql, short* __restrict__ Kh, short* __restrict__ Kl,
    f16* __restrict__ Vm, float* __restrict__ Kpart) {
  __shared__ __align__(16) short sm4[2][4][128][32];  // 64 KB (double-buffer)
  const int lid = blockIdx.x + (blockIdx.y << 2);
  const int swz = ((lid & 7) << 5) + (lid >> 3);  // XCD-bijective (256=8x32)
  const int nt = swz & 3, mt = swz >> 2;
  const int m0 = mt * 128, n0 = nt * 128;
  const int z = blockIdx.z;
  if (z == 2) {
    gemm16_gll<f16>(Ym, vwT, vb, Vm, m0, n0, (f16(*)[128][32]) & sm4[0][0][0][0],
                    (f16(*)[128][32]) & sm4[0][2][0][0]);
    return;
  }
  const short* Agh = z ? Yh : Xh;
  const short* Agl = z ? Yl : Xl;
  const short* Wh = z ? kwh : qwh;
  const short* Wl = z ? kwl : qwl;
  const float* bias = z ? kbias : qb;
  short* Ch = z ? Kh : Qh;
  short* Cl = z ? Kl : Ql;
  const float osc = z ? 1.f : (float)QPROJ_SCALE;  // Q pre-scaled for attn

  const int tid = threadIdx.x;
  const int wv = tid >> 6, lane = tid & 63;
  const int wm = wv >> 1, wn = wv & 1;
  const int l15 = lane & 15, lg = lane >> 4;
  const int srow = lane >> 2, sslot = lane & 3;

  // wave wv stages stream wv: 0=A-hi, 1=A-lo, 2=B-hi, 3=B-lo (8 KB each)
  const short* gsb = (wv == 0) ? Agh : (wv == 1) ? Agl : (wv == 2) ? Wh : Wl;
  const int rb = (wv < 2) ? m0 : n0;

  const f32x4 fz = {0.f, 0.f, 0.f, 0.f};
  f32x4 acc[4][4];
#pragma unroll
  for (int m = 0; m < 4; ++m)
#pragma unroll
    for (int n = 0; n < 4; ++n) acc[m][n] = fz;

  PSTAGE(0, 0);  // prologue
  int cur = 0;
  for (int k0 = 0; k0 < 512; k0 += 32) {
    __syncthreads();  // drains prefetch -> buf[cur] ready; prev reads done
    if (k0 < 480) PSTAGE(cur ^ 1, k0 + 32);  // in flight under compute
    bf16x8 afh[4], afl[4], bfh[4], bfl[4];
#pragma unroll
    for (int m = 0; m < 4; ++m) {
      const int r = wm * 64 + m * 16 + l15;
      const int sl = (lg ^ ((r >> 1) & 3)) * 8;
      afh[m] = *(const bf16x8*)&sm4[cur][0][r][sl];
      afl[m] = *(const bf16x8*)&sm4[cur][1][r][sl];
    }
#pragma unroll
    for (int n = 0; n < 4; ++n) {
      const int r = wn * 64 + n * 16 + l15;
      const int sl = (lg ^ ((r >> 1) & 3)) * 8;
      bfh[n] = *(const bf16x8*)&sm4[cur][2][r][sl];
      bfl[n] = *(const bf16x8*)&sm4[cur][3][r][sl];
    }
#pragma unroll
    for (int m = 0; m < 4; ++m)
#pragma unroll
      for (int n = 0; n < 4; ++n) {
        acc[m][n] = MFMAB16(afh[m], bfh[n], acc[m][n]);
        acc[m][n] = MFMAB16(afh[m], bfl[n], acc[m][n]);
        acc[m][n] = MFMAB16(afl[m], bfh[n], acc[m][n]);
      }
    cur ^= 1;
  }
  // epilogue: split-bf16 output (+ deterministic K column partial sums)
  float csum[4];
#pragma unroll
  for (int n = 0; n < 4; ++n) {
    const int col = n0 + wn * 64 + n * 16 + l15;
    const float b = bias[col];
    csum[n] = 16.f * b;
#pragma unroll
    for (int m = 0; m < 4; ++m) {
      const int row = m0 + wm * 64 + m * 16 + lg * 4;
#pragma unroll
      for (int r = 0; r < 4; ++r) {
        const float vraw = acc[m][n][r] + b;
        csum[n] += acc[m][n][r];
        short h, l;
        splitbf(vraw * osc, h, l);
        const size_t idx = (size_t)(row + r) * 512 + col;
        Ch[idx] = h;
        Cl[idx] = l;
      }
    }
  }
  if (z == 1) {
    // block-local column reduction (deterministic): 128 cols x 8 contributors
    float* cred = (float*)&sm4[0][0][0][0];
    __syncthreads();  // all waves done with LDS tiles
#pragma unroll
    for (int n = 0; n < 4; ++n)
      cred[(wn * 64 + n * 16 + l15) * 8 + wm * 4 + lg] = csum[n];
    __syncthreads();
    if (tid < 64) {
      float s = 0.f;
#pragma unroll
      for (int j = 0; j < 8; ++j)
        s += cred[tid * 8 + j] + cred[(tid + 64) * 8 + j];
      Kpart[((size_t)mt * 4 + nt) * 64 + tid] = s;  // mt == problem p
    }
  }
}

// ----------------------- V transpose (per problem) -------------------------
// Vm [8192][512] f16 -> Vt [64 p][64 dh][1024 k] f16.
__global__ __launch_bounds__(256) void k_vtr(const f16* __restrict__ Vm,
                                             f16* __restrict__ Vt) {
  const int p = blockIdx.y;
  const int j0 = blockIdx.x * 16;
  __shared__ f16 L[16][520];
  const int tid = threadIdx.x;
#pragma unroll
  for (int it = 0; it < 4; ++it) {
    int idx = it * 256 + tid;
    int row = idx >> 6, oct = idx & 63;
    *(f16x8*)&L[row][oct * 8] =
        *(const f16x8*)&Vm[(size_t)(p * 128 + j0 + row) * 512 + oct * 8];
  }
  __syncthreads();
#pragma unroll
  for (int it = 0; it < 4; ++it) {
    int idx = it * 256 + tid;
    int dh = idx >> 4, j = idx & 15;
    f16x8 v;
#pragma unroll
    for (int g = 0; g < 8; ++g) v[g] = L[j][g * 64 + dh];
    *(f16x8*)&Vt[((size_t)p * 64 + dh) * 1024 + (j0 + j) * 8] = v;
  }
}

// ------------------------------- attention ---------------------------------
// grid (64 problems, 8 q-tiles), 512 threads = 8 waves.
// Wave w: q-group qg=w&3 (32 q = 2x16) x key-half (w>>2) (2 t-tiles/chunk).
// K/V fragments read ONCE per wave feed both q-groups -> LDS reads/wave/chunk
// = 8 b128 + 8 b64 (half of round 13); per-wave MFMA unchanged (44/chunk).
// Wave pairs (w, w+4) merge partial O/den via reused staging LDS at the end.
#define STAGE(b, cc)                                       \
  {                                                        \
    GLL16(KhSrc + (cc) * 4096, &KhS[b][skey][slot8 * 8]);  \
    GLL16(KlSrc + (cc) * 4096, &KlS[b][skey][slot8 * 8]);  \
    GLL16(VSrc + (cc) * 64, &Vs[b][skey][slot8 * 8]);      \
  }

// one 64-key chunk with compile-time buffer index cb_
#define CHUNK(cb_, c_)                                                        \
  {                                                                           \
    __syncthreads(); /* drains STAGE of buf[cb_]; prev buf reads done */      \
    if ((c_) < 15) STAGE((cb_) ^ 1, (c_) + 1); /* async under compute */      \
    __builtin_amdgcn_s_setprio(1);                                            \
    _Pragma("unroll") for (int th = 0; th < 2; ++th) {                        \
      const int t = tbase + th;                                               \
      const int krow = t * 16 + l15;                                          \
      const int ksw = l15 & 7; /* krow&7 == l15&7 */                          \
      bf16x8 kh0 = *(const bf16x8*)&KhS[cb_][krow][(lg ^ ksw) * 8];           \
      bf16x8 kh1 = *(const bf16x8*)&KhS[cb_][krow][((4 + lg) ^ ksw) * 8];     \
      bf16x8 kl0 = *(const bf16x8*)&KlS[cb_][krow][(lg ^ ksw) * 8];           \
      bf16x8 kl1 = *(const bf16x8*)&KlS[cb_][krow][((4 + lg) ^ ksw) * 8];     \
      f32x4 a0 = fz, a1 = fz; /* two independent chains (q-groups) */         \
      a0 = MFMAB16(kh0, q0h0, a0);                                            \
      a1 = MFMAB16(kh0, q1h0, a1);                                            \
      a0 = MFMAB16(kh1, q0h1, a0);                                            \
      a1 = MFMAB16(kh1, q1h1, a1);                                            \
      a0 = MFMAB16(kl0, q0h0, a0);                                            \
      a1 = MFMAB16(kl0, q1h0, a1);                                            \
      a0 = MFMAB16(kh0, q0l0, a0);                                            \
      a1 = MFMAB16(kh0, q1l0, a1);                                            \
      a0 = MFMAB16(kl1, q0h1, a0);                                            \
      a1 = MFMAB16(kl1, q1h1, a1);                                            \
      a0 = MFMAB16(kh1, q0l1, a0);                                            \
      a1 = MFMAB16(kh1, q1l1, a1);                                            \
      f16x4 pf0, pf1;                                                         \
      _Pragma("unroll") for (int r = 0; r < 4; ++r) {                         \
        float v0 = a0[r];                                                     \
        pf0[r] = (f16)((v0 > sm0) ? EXPFN(v0) : 0.f);                         \
        float v1 = a1[r];                                                     \
        pf1[r] = (f16)((v1 > sm1) ? EXPFN(v1) : 0.f);                         \
      }                                                                       \
      od0 = MFMAPV(kones, pf0, od0);                                          \
      od1 = MFMAPV(kones, pf1, od1);                                          \
      _Pragma("unroll") for (int d0 = 0; d0 < 4; ++d0) {                      \
        const int vrow = d0 * 16 + l15;                                       \
        const int vsw = l15 & 7;                                              \
        f16x4 va = *(const f16x4*)&Vs[cb_][vrow]                              \
                       [(((t * 2 + (lg >> 1)) ^ vsw) * 8) + (lg & 1) * 4];    \
        oac0[d0] = MFMAPV(va, pf0, oac0[d0]);                                 \
        oac1[d0] = MFMAPV(va, pf1, oac1[d0]);                                 \
      }                                                                       \
    }                                                                         \
    __builtin_amdgcn_s_setprio(0);                                            \
  }

__global__ __launch_bounds__(512, 4) void k_attn(
    const short* __restrict__ Qh, const short* __restrict__ Ql,
    const short* __restrict__ Kh, const short* __restrict__ Kl,
    const f16* __restrict__ Vt, const float* __restrict__ Kpart,
    f16* __restrict__ Om) {
  constexpr int S = 1024, DH = 64;
  const int p = blockIdx.x;
  const int qt = blockIdx.y;
  const size_t pb = (size_t)p * S * DH;
  const short* Qhp = Qh + pb;
  const short* Qlp = Ql + pb;
  const short* Khp = Kh + pb;
  const short* Klp = Kl + pb;
  const f16* Vtp = Vt + pb;  // [64 dh][1024 k]
  f16* Op = Om + pb;

  const int tid = threadIdx.x;
  const int w = tid >> 6, lane = tid & 63;
  const int l15 = lane & 15, lg = lane >> 4;
  const int qg = w & 3;            // q-group (32 q)
  const int tbase = (w >> 2) * 2;  // key-half: t-tiles {tbase, tbase+1}

  __shared__ __align__(16) char smem[49152];  // staging; reused for merge
  short(*KhS)[64][64] = (short(*)[64][64])smem;             // 16 KB
  short(*KlS)[64][64] = (short(*)[64][64])(smem + 16384);   // 16 KB
  f16(*Vs)[64][64] = (f16(*)[64][64])(smem + 32768);        // 16 KB

  // GLL staging (unchanged): source pre-swizzled, LDS dest linear.
  const int skey = tid >> 3;
  const int slot8 = tid & 7;
  const int ssw = skey & 7;
  const short* KhSrc = Khp + skey * 64 + (slot8 ^ ssw) * 8;
  const short* KlSrc = Klp + skey * 64 + (slot8 ^ ssw) * 8;
  const f16* VSrc = Vtp + (size_t)skey * 1024 + (slot8 ^ ssw) * 8;

  STAGE(0, 0);  // async; drained by the first barrier

  // this wave's two 16-q groups (Q pre-scaled by QPROJ_SCALE)
  const int qrow = qt * 128 + qg * 32;
  const size_t qo0 = (size_t)(qrow + l15) * DH + lg * 8;
  const size_t qo1 = (size_t)(qrow + 16 + l15) * DH + lg * 8;
  bf16x8 q0h0 = *(const bf16x8*)(Qhp + qo0);
  bf16x8 q0l0 = *(const bf16x8*)(Qlp + qo0);
  bf16x8 q0h1 = *(const bf16x8*)(Qhp + qo0 + 32);
  bf16x8 q0l1 = *(const bf16x8*)(Qlp + qo0 + 32);
  bf16x8 q1h0 = *(const bf16x8*)(Qhp + qo1);
  bf16x8 q1l0 = *(const bf16x8*)(Qlp + qo1);
  bf16x8 q1h1 = *(const bf16x8*)(Qhp + qo1 + 32);
  bf16x8 q1l1 = *(const bf16x8*)(Qlp + qo1 + 32);

  // thresholds: mean_q = (Qscaled_q . Ksum) / 1024
  const float* kp = Kpart + (size_t)p * 256;
  float km0[8], km1[8];
#pragma unroll
  for (int j = 0; j < 8; ++j) { km0[j] = 0.f; km1[j] = 0.f; }
#pragma unroll
  for (int pt = 0; pt < 4; ++pt) {
    const float* bb = kp + pt * 64;
#pragma unroll
    for (int j = 0; j < 8; ++j) {
      km0[j] += bb[lg * 8 + j];
      km1[j] += bb[32 + lg * 8 + j];
    }
  }
  float sm0 = 0.f, sm1 = 0.f;
#pragma unroll
  for (int j = 0; j < 8; ++j) {
    sm0 += (b2f(q0h0[j]) + b2f(q0l0[j])) * km0[j] +
           (b2f(q0h1[j]) + b2f(q0l1[j])) * km1[j];
    sm1 += (b2f(q1h0[j]) + b2f(q1l0[j])) * km0[j] +
           (b2f(q1h1[j]) + b2f(q1l1[j])) * km1[j];
  }
  sm0 += __shfl_xor(sm0, 16); sm0 += __shfl_xor(sm0, 32);
  sm1 += __shfl_xor(sm1, 16); sm1 += __shfl_xor(sm1, 32);
  sm0 *= (1.f / 1024.f);
  sm1 *= (1.f / 1024.f);

  const f32x4 fz = {0.f, 0.f, 0.f, 0.f};
  const f16x4 kones = {(f16)1.f, (f16)1.f, (f16)1.f, (f16)1.f};
  f32x4 oac0[4], oac1[4];
#pragma unroll
  for (int d = 0; d < 4; ++d) { oac0[d] = fz; oac1[d] = fz; }
  f32x4 od0 = fz, od1 = fz;

  for (int cc = 0; cc < 16; cc += 2) {
    CHUNK(0, cc);
    CHUNK(1, cc + 1);
  }

  // ---- cross-pair merge: waves (qg) and (qg+4) hold key-halves of same q --
  __syncthreads();  // all staging reads done; smem reusable
  float* MRG = (float*)smem;  // [4 qg][64 lane][34]: 34.8 KB
  if (w >= 4) {
    float* dst = MRG + ((size_t)qg * 64 + lane) * 34;
#pragma unroll
    for (int d0 = 0; d0 < 4; ++d0)
#pragma unroll
      for (int r = 0; r < 4; ++r) {
        dst[d0 * 4 + r] = oac0[d0][r];
        dst[16 + d0 * 4 + r] = oac1[d0][r];
      }
    dst[32] = od0[0];
    dst[33] = od1[0];
  }
  __syncthreads();
  if (w < 4) {
    const float* src = MRG + ((size_t)qg * 64 + lane) * 34;
    const float inv0 = 1.f / (od0[0] + src[32]);
    const float inv1 = 1.f / (od1[0] + src[33]);
#pragma unroll
    for (int d0 = 0; d0 < 4; ++d0) {
      f16x4 o0, o1;
#pragma unroll
      for (int r = 0; r < 4; ++r) {
        o0[r] = (f16)((oac0[d0][r] + src[d0 * 4 + r]) * inv0);
        o1[r] = (f16)((oac1[d0][r] + src[16 + d0 * 4 + r]) * inv1);
      }
      *(f16x4*)&Op[(size_t)(qrow + l15) * DH + d0 * 16 + lg * 4] = o0;
      *(f16x4*)&Op[(size_t)(qrow + 16 + l15) * DH + d0 * 16 + lg * 4] = o1;
    }
  }
}

// ------------------------------- launcher ----------------------------------
extern "C" void kernel_launch(void* const* d_in, const int* in_sizes, int n_in,
                              void* d_out, int out_size, void* d_ws,
                              size_t ws_size, hipStream_t stream) {
  const float* x = (const float*)d_in[0];
  const float* y = (const float*)d_in[1];
  const float* qw = (const float*)d_in[2];
  const float* qb = (const float*)d_in[3];
  const float* kw = (const float*)d_in[4];
  const float* kbias = (const float*)d_in[5];
  const float* vw = (const float*)d_in[6];
  const float* vb = (const float*)d_in[7];
  const float* ow = (const float*)d_in[8];
  const float* ob = (const float*)d_in[9];
  float* out = (float*)d_out;

  char* ws = (char*)d_ws;
  const size_t WT_B = 512ull * 512 * 2;    // 512 KB
  const size_t MAT_B = 8192ull * 512 * 2;  // 8 MB
  short* qwhT = (short*)(ws + 0 * WT_B);
  short* qwlT = (short*)(ws + 1 * WT_B);
  short* kwhT = (short*)(ws + 2 * WT_B);
  short* kwlT = (short*)(ws + 3 * WT_B);
  f16* vwT = (f16*)(ws + 4 * WT_B);
  f16* owT = (f16*)(ws + 5 * WT_B);
  char* m = ws + 6 * WT_B;
  short* Qh = (short*)(m + 0 * MAT_B);
  short* Ql = (short*)(m + 1 * MAT_B);
  short* Kh = (short*)(m + 2 * MAT_B);
  short* Kl = (short*)(m + 3 * MAT_B);
  f16* Vm = (f16*)(m + 4 * MAT_B);
  short* Xh = (short*)(m + 5 * MAT_B);
  short* Xl = (short*)(m + 6 * MAT_B);
  short* Yh = (short*)(m + 7 * MAT_B);
  short* Yl = (short*)(m + 8 * MAT_B);
  f16* Ym = (f16*)(m + 9 * MAT_B);
  float* Kpart = (float*)(m + 10 * MAT_B);  // 64 KB; total ~83.1 MB
  // dead-buffer aliases (stream order makes these safe):
  f16* Vtr = (f16*)Xh;  // k_vtr runs after k_proj (Xh consumed)
  f16* Om = (f16*)Yh;   // k_attn runs after k_proj (Yh consumed)

  hipLaunchKernelGGL(k_pre, dim3(2048, 2), dim3(256), 0, stream, x, y, qw, kw,
                     vw, ow, qwhT, qwlT, kwhT, kwlT, vwT, owT, Xh, Xl, Yh, Yl,
                     Ym);
  hipLaunchKernelGGL(k_proj, dim3(4, 64, 3), dim3(256), 0, stream, Xh, Xl, Yh,
                     Yl, Ym, qwhT, qwlT, kwhT, kwlT, vwT, qb, kbias, vb, Qh,
                     Ql, Kh, Kl, Vm, Kpart);
  hipLaunchKernelGGL(k_vtr, dim3(8, 64), dim3(256), 0, stream, Vm, Vtr);
  hipLaunchKernelGGL(k_attn, dim3(64, 8), dim3(512), 0, stream, Qh, Ql, Kh,
                     Kl, Vtr, Kpart, Om);
  hipLaunchKernelGGL(k_gemm_out, dim3(8, 64), dim3(256), 0, stream, Om, owT,
                     ob, out);
}